// Round 2
// baseline (2604.734 us; speedup 1.0000x reference)
//
#include <hip/hip_runtime.h>
#include <limits.h>

// ---------------- problem constants ----------------
#define T_STEPS 15
#define CIN     6
#define HIN     252
#define WIN_    252
#define C1      30
#define PH      126      // pooled H/W
#define SH      128      // padded spike map H/W
#define SW      128
#define C2      250
#define NPIX    (126*126)   // 15876
#define THR1    15.0f
#define THR2    10.0f
#define KWTA    8

#define SPK_ELEMS  59535000L   // 15*250*126*126

// ---------------- K1: conv1 + fire + 2x2 maxpool(OR) + pad1 ----------------
// one thread per (t, c, ph, pw); computes 4 conv outputs (the 2x2 pool window)
__global__ __launch_bounds__(256) void conv1_fire_pool(
    const int* __restrict__ inp, const float* __restrict__ w1,
    float* __restrict__ spk_in) {
  long idx = (long)blockIdx.x * 256 + threadIdx.x;
  const long total = (long)T_STEPS * C1 * NPIX;
  if (idx >= total) return;
  int pw = (int)(idx % 126); long tmp = idx / 126;
  int ph = (int)(tmp % 126); tmp /= 126;
  int c  = (int)(tmp % C1);
  int t  = (int)(tmp / C1);

  const int* in_t = inp + (long)t * CIN * HIN * WIN_;
  const float* wbase = w1 + c * (CIN * 25);

  float p00 = 0.f, p01 = 0.f, p10 = 0.f, p11 = 0.f;
  int r0 = 2 * ph - 2;
  int c0 = 2 * pw - 2;

  for (int ic = 0; ic < CIN; ++ic) {
    const int* in_c = in_t + ic * (HIN * WIN_);
    float win[7][7];
    #pragma unroll
    for (int i = 0; i < 7; ++i) {
      int r = r0 + i;
      bool rok = (r >= 0) && (r < HIN);
      #pragma unroll
      for (int j = 0; j < 7; ++j) {
        int cc = c0 + j;
        win[i][j] = (rok && cc >= 0 && cc < WIN_) ? (float)in_c[r * WIN_ + cc] : 0.0f;
      }
    }
    const float* wc = wbase + ic * 25;
    #pragma unroll
    for (int kh = 0; kh < 5; ++kh) {
      #pragma unroll
      for (int kw = 0; kw < 5; ++kw) {
        float wv = wc[kh * 5 + kw];
        p00 = fmaf(wv, win[kh][kw],     p00);
        p01 = fmaf(wv, win[kh][kw + 1], p01);
        p10 = fmaf(wv, win[kh + 1][kw], p10);
        p11 = fmaf(wv, win[kh + 1][kw + 1], p11);
      }
    }
  }
  bool any = (p00 > THR1) || (p01 > THR1) || (p10 > THR1) || (p11 > THR1);
  spk_in[(((long)t * C1 + c) * SH + (ph + 1)) * SW + (pw + 1)] = any ? 1.0f : 0.0f;
}

// ---------------- K2: conv2 + fire + per-(t,pixel) max/argmax ----------------
// block = 16x16 pixel tile, one t per blockIdx.z. Spikes staged in LDS,
// weights via wave-uniform scalar loads, 25 feature accumulators per thread.
#define FCH 25
__global__ __launch_bounds__(256) void conv2_fire(
    const float* __restrict__ spk_in, const float* __restrict__ w2,
    float* __restrict__ pot_reg, float* __restrict__ meta_max,
    int* __restrict__ meta_idx) {
  __shared__ float s_spk[C1][18][18];
  const int t = blockIdx.z;
  const int h0 = blockIdx.y * 16, w0 = blockIdx.x * 16;
  const int tid = threadIdx.y * 16 + threadIdx.x;

  const float* sp_t = spk_in + (long)t * C1 * SH * SW;
  for (int i = tid; i < C1 * 18 * 18; i += 256) {
    int c = i / 324; int rem = i % 324; int r = rem / 18; int col = rem % 18;
    int gh = h0 + r, gw = w0 + col;
    s_spk[c][r][col] = (gh < SH && gw < SW) ? sp_t[(c * SH + gh) * SW + gw] : 0.0f;
  }
  __syncthreads();

  const int oh = h0 + threadIdx.y, ow = w0 + threadIdx.x;
  const bool active = (oh < 126) && (ow < 126);
  float maxv = 0.0f; int maxi = 0;
  float* pot_base = pot_reg + (long)t * C2 * NPIX + oh * 126 + ow;

  for (int f0 = 0; f0 < C2; f0 += FCH) {
    float acc[FCH];
    #pragma unroll
    for (int f = 0; f < FCH; ++f) acc[f] = 0.0f;

    for (int c = 0; c < C1; ++c) {
      float s[3][3];
      #pragma unroll
      for (int i = 0; i < 3; ++i)
        #pragma unroll
        for (int j = 0; j < 3; ++j)
          s[i][j] = s_spk[c][threadIdx.y + i][threadIdx.x + j];

      const float* wc = w2 + (long)f0 * (C1 * 9) + c * 9;
      #pragma unroll
      for (int f = 0; f < FCH; ++f) {
        const float* wf = wc + f * (C1 * 9);
        #pragma unroll
        for (int kh = 0; kh < 3; ++kh)
          #pragma unroll
          for (int kw = 0; kw < 3; ++kw)
            acc[f] = fmaf(wf[kh * 3 + kw], s[kh][kw], acc[f]);
      }
    }

    if (active) {
      #pragma unroll
      for (int f = 0; f < FCH; ++f) {
        float pt = (acc[f] > THR2) ? acc[f] : 0.0f;
        if (pt > maxv) { maxv = pt; maxi = f0 + f; }   // strict > = first-max (argmax)
        pot_base[(long)(f0 + f) * NPIX] = pt;
      }
    }
  }
  if (active) {
    meta_max[t * NPIX + oh * 126 + ow] = maxv;
    meta_idx[t * NPIX + oh * 126 + ow] = maxi;
  }
}

// ---------------- K3: per-pixel winner feature ----------------
__global__ __launch_bounds__(256) void inhibit_meta(
    const float* __restrict__ meta_max, const int* __restrict__ meta_idx,
    int* __restrict__ winfeat) {
  int p = blockIdx.x * 256 + threadIdx.x;
  if (p >= NPIX) return;
  int nf = 0; bool last = false;
  #pragma unroll
  for (int t = 0; t < T_STEPS; ++t) {
    bool f = meta_max[t * NPIX + p] > 0.0f;
    nf += f ? 1 : 0;
    if (t == T_STEPS - 1) last = f;
  }
  int earliest = T_STEPS - nf;               // >= 0
  if (earliest > T_STEPS - 1) earliest = T_STEPS - 1;
  int wf = meta_idx[earliest * NPIX + p];
  winfeat[p] = last ? wf : -1;
}

// ---------------- K4: apply inhibition, write spk + pot ----------------
__global__ __launch_bounds__(256) void finalize(
    const int* __restrict__ winfeat, float* __restrict__ pot_reg,
    float* __restrict__ spk_reg) {
  long i = (long)blockIdx.x * 256 + threadIdx.x;   // float4 index
  const long total4 = SPK_ELEMS / 4;
  if (i >= total4) return;
  long e = i * 4;
  int p = (int)(e % NPIX);                  // NPIX % 4 == 0, no wrap within float4
  long tf = e / NPIX;
  int f = (int)(tf % C2);

  float4 pv = ((const float4*)pot_reg)[i];
  int w0 = winfeat[p], w1_ = winfeat[p + 1], w2_ = winfeat[p + 2], w3 = winfeat[p + 3];
  float4 po, sp;
  po.x = (w0 == f) ? pv.x : 0.0f;  sp.x = (po.x > 0.0f) ? 1.0f : 0.0f;
  po.y = (w1_ == f) ? pv.y : 0.0f; sp.y = (po.y > 0.0f) ? 1.0f : 0.0f;
  po.z = (w2_ == f) ? pv.z : 0.0f; sp.z = (po.z > 0.0f) ? 1.0f : 0.0f;
  po.w = (w3 == f) ? pv.w : 0.0f;  sp.w = (po.w > 0.0f) ? 1.0f : 0.0f;
  ((float4*)pot_reg)[i] = po;
  ((float4*)spk_reg)[i] = sp;
}

// ---------------- K5a: per-pixel candidate (nspk, value-at-earliest) ----------------
__global__ __launch_bounds__(256) void kwin_prep(
    const int* __restrict__ winfeat, const float* __restrict__ pot_reg,
    float* __restrict__ cand_val, int* __restrict__ cand_n) {
  int p = blockIdx.x * 256 + threadIdx.x;
  if (p >= NPIX) return;
  int w = winfeat[p];
  float value = 0.0f; int n = 0;
  if (w >= 0) {
    #pragma unroll
    for (int t = 0; t < T_STEPS; ++t) {
      float v = pot_reg[((long)t * C2 + w) * NPIX + p];
      n += (v > 0.0f) ? 1 : 0;
    }
    int e = T_STEPS - n;                     // n>=1 when w>=0 in the monotone case
    if (e > T_STEPS - 1) e = T_STEPS - 1;
    if (e < 0) e = 0;
    value = pot_reg[((long)e * C2 + w) * NPIX + p];
  }
  cand_val[p] = value;
  cand_n[p] = n;
}

// ---------------- K5b: 8 rounds of argmax + NMS, single block ----------------
__global__ __launch_bounds__(1024) void kwin_select(
    const float* __restrict__ cand_val, const int* __restrict__ cand_n,
    const int* __restrict__ winfeat, float* __restrict__ winners_out) {
  __shared__ float r_val[1024];
  __shared__ int   r_idx[1024];
  __shared__ unsigned char featrem[C2];
  __shared__ unsigned char rem[NPIX];
  __shared__ int s_rw, s_cw;
  const int tid = threadIdx.x;

  for (int i = tid; i < C2; i += 1024) featrem[i] = 0;
  for (int i = tid; i < NPIX; i += 1024) rem[i] = 0;

  // v = T * max(trunc) = 15 * max(cand_val)
  float m = 0.0f;
  for (int i = tid; i < NPIX; i += 1024) m = fmaxf(m, cand_val[i]);
  r_val[tid] = m;
  __syncthreads();
  for (int s = 512; s > 0; s >>= 1) {
    if (tid < s) r_val[tid] = fmaxf(r_val[tid], r_val[tid + s]);
    __syncthreads();
  }
  const float v = r_val[0] * (float)T_STEPS;
  __syncthreads();

  for (int round = 0; round < KWTA; ++round) {
    float bv = 0.0f; int bi = INT_MAX;
    for (int p = tid; p < NPIX; p += 1024) {
      if (rem[p]) continue;
      int w = winfeat[p];
      if (w < 0 || featrem[w]) continue;
      float tot = (float)cand_n[p] * (cand_val[p] + v);
      int flat = w * NPIX + p;               // c-major flat index (ties -> min)
      if (tot > bv || (tot == bv && flat < bi)) { bv = tot; bi = flat; }
    }
    r_val[tid] = bv; r_idx[tid] = bi;
    __syncthreads();
    for (int s = 512; s > 0; s >>= 1) {
      if (tid < s) {
        float ov = r_val[tid + s]; int oi = r_idx[tid + s];
        if (ov > r_val[tid] || (ov == r_val[tid] && oi < r_idx[tid])) {
          r_val[tid] = ov; r_idx[tid] = oi;
        }
      }
      __syncthreads();
    }
    if (tid == 0) {
      float mv = r_val[0]; int fi = r_idx[0];
      if (mv > 0.0f && fi != INT_MAX) {
        int c = fi / NPIX; int p = fi % NPIX;
        int row = p / 126, col = p % 126;
        winners_out[round * 3 + 0] = (float)c;
        winners_out[round * 3 + 1] = (float)row;
        winners_out[round * 3 + 2] = (float)col;
        featrem[c] = 1;
        s_rw = row; s_cw = col;
      } else {
        winners_out[round * 3 + 0] = -1.0f;
        winners_out[round * 3 + 1] = -1.0f;
        winners_out[round * 3 + 2] = -1.0f;
        s_rw = -10; s_cw = -10;
      }
    }
    __syncthreads();
    int rw = s_rw, cw = s_cw;
    if (rw >= 0) {
      for (int p = tid; p < NPIX; p += 1024) {
        int row = p / 126, col = p % 126;
        if (row >= rw - 1 && row <= rw + 1 && col >= cw - 1 && col <= cw + 1) rem[p] = 1;
      }
    }
    __syncthreads();
  }
}

// ---------------- launch ----------------
extern "C" void kernel_launch(void* const* d_in, const int* in_sizes, int n_in,
                              void* d_out, int out_size, void* d_ws, size_t ws_size,
                              hipStream_t stream) {
  const int*   inp = (const int*)d_in[0];
  // d_in[1] = max_layer scalar (ignored; always 2)
  const float* w1  = (const float*)d_in[2];
  const float* w2  = (const float*)d_in[3];

  float* out = (float*)d_out;
  float* spk_reg = out;                       // [15,250,126,126]
  float* pot_reg = out + SPK_ELEMS;           // [15,250,126,126]
  float* win_reg = out + 2 * SPK_ELEMS;       // [8,3]

  float* ws = (float*)d_ws;
  float* spk_in   = ws;                                   // 15*30*128*128 = 7,372,800
  float* meta_max = ws + 7372800;                         // 15*15876     =   238,140
  int*   meta_idx = (int*)ws + 7610940;                   //   238,140
  int*   winfeat  = (int*)ws + 7849080;                   //    15,876
  float* cand_val = ws + 7864956;                         //    15,876
  int*   cand_n   = (int*)ws + 7880832;                   //    15,876

  // zero padded spike map (covers the pad-1 border); ws is poisoned every call
  hipMemsetAsync(spk_in, 0, 7372800 * sizeof(float), stream);

  {
    long total = (long)T_STEPS * C1 * NPIX;                // 7,144,200
    int blocks = (int)((total + 255) / 256);
    conv1_fire_pool<<<blocks, 256, 0, stream>>>(inp, w1, spk_in);
  }
  {
    dim3 g(8, 8, T_STEPS), b(16, 16);
    conv2_fire<<<g, b, 0, stream>>>(spk_in, w2, pot_reg, meta_max, meta_idx);
  }
  inhibit_meta<<<(NPIX + 255) / 256, 256, 0, stream>>>(meta_max, meta_idx, winfeat);
  {
    long total4 = SPK_ELEMS / 4;
    int blocks = (int)((total4 + 255) / 256);
    finalize<<<blocks, 256, 0, stream>>>(winfeat, pot_reg, spk_reg);
  }
  kwin_prep<<<(NPIX + 255) / 256, 256, 0, stream>>>(winfeat, pot_reg, cand_val, cand_n);
  kwin_select<<<1, 1024, 0, stream>>>(cand_val, cand_n, winfeat, win_reg);
}

// Round 4
// 1302.975 us; speedup vs baseline: 1.9991x; 1.9991x over previous
//
#include <hip/hip_runtime.h>
#include <limits.h>

#define T_STEPS 15
#define CIN     6
#define HIN     252
#define WIN_    252
#define C1      30
#define SH      128
#define SW      128
#define C2      250
#define NPIX    (126*126)   // 15876
#define THR1    15.0f
#define THR2    10.0f
#define KWTA    8
#define SPK_ELEMS  59535000L   // 15*250*126*126

// ================= K1: conv1 + fire + 2x2 pool(OR) + pad1 =================
// block 128 lanes = pw (0..125 used); grid (18 ph-strips of 7, 30 c, 15 t).
__global__ __launch_bounds__(128) void conv1_v2(
    const int* __restrict__ inp, const float* __restrict__ w1,
    float* __restrict__ spk_in) {
  const int pw = threadIdx.x;
  const int ph0 = blockIdx.x * 7;
  const int c = blockIdx.y;
  const int t = blockIdx.z;

  float a[28];   // [li][e], li=conv row - 2*ph0 (0..13), e=conv col (2pw+e)
  #pragma unroll
  for (int i = 0; i < 28; ++i) a[i] = 0.f;

  const int cbase = 2 * pw - 2;
  for (int ic = 0; ic < CIN; ++ic) {
    const float* wc = w1 + (c * CIN + ic) * 25;           // uniform -> SGPR
    const int* base = inp + ((long)(t * CIN + ic) * HIN) * WIN_;
    #pragma unroll
    for (int rr = 0; rr < 18; ++rr) {
      int r = 2 * ph0 - 2 + rr;
      if (r >= 0 && r < HIN) {                            // uniform branch
        const int* rp = base + r * WIN_;
        float in6[6];
        #pragma unroll
        for (int j = 0; j < 6; ++j) {
          int col = cbase + j;
          int cc = col < 0 ? 0 : (col > 251 ? 251 : col);
          float v = (float)rp[cc];
          in6[j] = (col == cc) ? v : 0.f;
        }
        #pragma unroll
        for (int kh = 0; kh < 5; ++kh) {
          int li = rr - kh;                                // compile-time
          if (li >= 0 && li < 14) {
            #pragma unroll
            for (int kw = 0; kw < 5; ++kw) {
              float wv = wc[kh * 5 + kw];
              a[li * 2 + 0] = fmaf(wv, in6[kw],     a[li * 2 + 0]);
              a[li * 2 + 1] = fmaf(wv, in6[kw + 1], a[li * 2 + 1]);
            }
          }
        }
      }
    }
  }
  if (pw < 126) {
    #pragma unroll
    for (int pp = 0; pp < 7; ++pp) {
      bool fired = (a[(2*pp)*2] > THR1) || (a[(2*pp)*2+1] > THR1) ||
                   (a[(2*pp+1)*2] > THR1) || (a[(2*pp+1)*2+1] > THR1);
      spk_in[(((long)t * C1 + c) * SH + (ph0 + pp + 1)) * SW + (pw + 1)] =
          fired ? 1.0f : 0.0f;
    }
  }
}

// ============ K2: conv2 + fire -> per-(t,pixel) max/argmax only ============
// thread = feature f; strip of 42 pixels; grid (3, 126 rows, 15 t).
// Accumulation order per output: c asc, kh asc, kw asc (bitwise = reference).
__global__ __launch_bounds__(256, 4) void conv2_meta(
    const float* __restrict__ spk_in, const float* __restrict__ w2,
    float* __restrict__ meta_val, int* __restrict__ meta_f) {
  const int f = threadIdx.x;
  const int px0 = blockIdx.x * 42;
  const int oh = blockIdx.y;
  const int t = blockIdx.z;
  const bool valid_f = (f < C2);

  const float* sbase = spk_in + ((long)(t * C1) * SH + oh) * SW + px0; // uniform
  const float* wbase = w2 + (long)(valid_f ? f : 0) * 270;

  float acc[42];
  #pragma unroll
  for (int p = 0; p < 42; ++p) acc[p] = 0.f;

  for (int c = 0; c < C1; ++c) {
    float w[9];
    #pragma unroll
    for (int k = 0; k < 9; ++k) w[k] = wbase[c * 9 + k];
    #pragma unroll
    for (int kh = 0; kh < 3; ++kh) {
      const float* rp = sbase + (c * SH + kh) * SW;       // uniform address
      float row[44];
      #pragma unroll
      for (int j = 0; j < 44; ++j) row[j] = rp[j];
      #pragma unroll
      for (int kw = 0; kw < 3; ++kw) {
        #pragma unroll
        for (int p = 0; p < 42; ++p)
          acc[p] = fmaf(w[kh * 3 + kw], row[p + kw], acc[p]);
      }
    }
  }
  // threshold
  #pragma unroll
  for (int p = 0; p < 42; ++p)
    acc[p] = (valid_f && acc[p] > THR2) ? acc[p] : 0.f;

  // per-pixel argmax over f (first-max = min f on ties), chunked 3x14
  __shared__ float s_red[256][15];
  __shared__ float s_pv[16][15];
  __shared__ int   s_pf[16][15];
  const int tid = threadIdx.x;
  for (int chunk = 0; chunk < 3; ++chunk) {
    __syncthreads();
    #pragma unroll
    for (int j = 0; j < 14; ++j) s_red[tid][j] = acc[chunk * 14 + j];
    __syncthreads();
    if (tid < 224) {
      int g = tid / 14, j = tid % 14;
      float bv = -1.f; int bf = 0;
      for (int i = 0; i < 16; ++i) {
        float v = s_red[g * 16 + i][j];
        if (v > bv) { bv = v; bf = g * 16 + i; }
      }
      s_pv[g][j] = bv; s_pf[g][j] = bf;
    }
    __syncthreads();
    if (tid < 14) {
      int j = tid;
      float bv = -1.f; int bf = 0;
      for (int g = 0; g < 16; ++g) {
        float v = s_pv[g][j];
        if (v > bv) { bv = v; bf = s_pf[g][j]; }
      }
      int mp = t * NPIX + oh * 126 + px0 + chunk * 14 + j;
      meta_val[mp] = bv;          // 0 if nothing fired
      meta_f[mp] = bf;            // argmax (0 when all-zero, = ref argmax)
    }
  }
}

// ================= K3: per-pixel winner feature =================
__global__ __launch_bounds__(256) void inhibit2(
    const float* __restrict__ meta_val, const int* __restrict__ meta_f,
    int* __restrict__ winfeat) {
  int p = blockIdx.x * 256 + threadIdx.x;
  if (p >= NPIX) return;
  int n = 0; bool last = false;
  #pragma unroll
  for (int t = 0; t < T_STEPS; ++t) {
    bool fr = meta_val[t * NPIX + p] > 0.f;
    n += fr ? 1 : 0;
    if (t == T_STEPS - 1) last = fr;
  }
  int e = T_STEPS - n;
  if (e > T_STEPS - 1) e = T_STEPS - 1;
  if (e < 0) e = 0;
  winfeat[p] = last ? meta_f[e * NPIX + p] : -1;
}

// ====== K4: recompute winner columns, scatter into zeroed out, cand ======
__global__ __launch_bounds__(256) void winner_recompute(
    const int* __restrict__ winfeat, const float* __restrict__ spk_in,
    const float* __restrict__ w2, float* __restrict__ spk_out,
    float* __restrict__ pot_out, float* __restrict__ cand_val,
    int* __restrict__ cand_n) {
  int p = blockIdx.x * 256 + threadIdx.x;
  if (p >= NPIX) return;
  int w = winfeat[p];
  if (w < 0) { cand_val[p] = 0.f; cand_n[p] = 0; return; }
  int oh = p / 126, ow = p % 126;

  float pv[T_STEPS];
  #pragma unroll
  for (int t = 0; t < T_STEPS; ++t) pv[t] = 0.f;

  const float* wb = w2 + (long)w * 270;
  for (int c = 0; c < C1; ++c) {
    float w9[9];
    #pragma unroll
    for (int k = 0; k < 9; ++k) w9[k] = wb[c * 9 + k];
    #pragma unroll
    for (int t = 0; t < T_STEPS; ++t) {
      const float* sb = spk_in + (((long)(t * C1 + c)) * SH + oh) * SW + ow;
      #pragma unroll
      for (int kh = 0; kh < 3; ++kh)
        #pragma unroll
        for (int kw = 0; kw < 3; ++kw)
          pv[t] = fmaf(w9[kh * 3 + kw], sb[kh * SW + kw], pv[t]);
    }
  }
  int n = 0;
  #pragma unroll
  for (int t = 0; t < T_STEPS; ++t) {
    float pt = (pv[t] > THR2) ? pv[t] : 0.f;
    pv[t] = pt;
    long o = ((long)t * C2 + w) * NPIX + p;
    pot_out[o] = pt;
    spk_out[o] = (pt > 0.f) ? 1.0f : 0.0f;
    n += (pt > 0.f) ? 1 : 0;
  }
  int e = T_STEPS - n;
  if (e > T_STEPS - 1) e = T_STEPS - 1;
  if (e < 0) e = 0;
  float cv = 0.f;
  #pragma unroll
  for (int t = 0; t < T_STEPS; ++t) if (t == e) cv = pv[t];
  cand_val[p] = cv;
  cand_n[p] = n;
}

// ============ K5: 8 rounds argmax + NMS (single block) ============
__global__ __launch_bounds__(1024) void kwin_select(
    const float* __restrict__ cand_val, const int* __restrict__ cand_n,
    const int* __restrict__ winfeat, float* __restrict__ winners_out) {
  __shared__ float r_val[1024];
  __shared__ int   r_idx[1024];
  __shared__ unsigned char featrem[C2];
  __shared__ unsigned char rem[NPIX];
  __shared__ int s_rw, s_cw;
  const int tid = threadIdx.x;

  for (int i = tid; i < C2; i += 1024) featrem[i] = 0;
  for (int i = tid; i < NPIX; i += 1024) rem[i] = 0;

  float m = 0.f;
  for (int i = tid; i < NPIX; i += 1024) m = fmaxf(m, cand_val[i]);
  r_val[tid] = m;
  __syncthreads();
  for (int s = 512; s > 0; s >>= 1) {
    if (tid < s) r_val[tid] = fmaxf(r_val[tid], r_val[tid + s]);
    __syncthreads();
  }
  const float v = r_val[0] * (float)T_STEPS;
  __syncthreads();

  for (int round = 0; round < KWTA; ++round) {
    float bv = 0.f; int bi = INT_MAX;
    for (int p = tid; p < NPIX; p += 1024) {
      if (rem[p]) continue;
      int w = winfeat[p];
      if (w < 0 || featrem[w]) continue;
      // tot = sequential sum of n copies of (val+v) — bitwise = reference
      float x = cand_val[p] + v;
      int n = cand_n[p];
      float tot = 0.f;
      for (int q = 0; q < n; ++q) tot += x;
      int flat = w * NPIX + p;
      if (tot > bv || (tot == bv && flat < bi)) { bv = tot; bi = flat; }
    }
    r_val[tid] = bv; r_idx[tid] = bi;
    __syncthreads();
    for (int s = 512; s > 0; s >>= 1) {
      if (tid < s) {
        float ov = r_val[tid + s]; int oi = r_idx[tid + s];
        if (ov > r_val[tid] || (ov == r_val[tid] && oi < r_idx[tid])) {
          r_val[tid] = ov; r_idx[tid] = oi;
        }
      }
      __syncthreads();
    }
    if (tid == 0) {
      float mv = r_val[0]; int fi = r_idx[0];
      if (mv > 0.f && fi != INT_MAX) {
        int c = fi / NPIX; int p = fi % NPIX;
        int row = p / 126, col = p % 126;
        winners_out[round * 3 + 0] = (float)c;
        winners_out[round * 3 + 1] = (float)row;
        winners_out[round * 3 + 2] = (float)col;
        featrem[c] = 1;
        s_rw = row; s_cw = col;
      } else {
        winners_out[round * 3 + 0] = -1.f;
        winners_out[round * 3 + 1] = -1.f;
        winners_out[round * 3 + 2] = -1.f;
        s_rw = -10; s_cw = -10;
      }
    }
    __syncthreads();
    int rw = s_rw, cw = s_cw;
    if (rw >= 0) {
      for (int p = tid; p < NPIX; p += 1024) {
        int row = p / 126, col = p % 126;
        if (row >= rw - 1 && row <= rw + 1 && col >= cw - 1 && col <= cw + 1)
          rem[p] = 1;
      }
    }
    __syncthreads();
  }
}

// ---------------- launch ----------------
extern "C" void kernel_launch(void* const* d_in, const int* in_sizes, int n_in,
                              void* d_out, int out_size, void* d_ws, size_t ws_size,
                              hipStream_t stream) {
  const int*   inp = (const int*)d_in[0];
  const float* w1  = (const float*)d_in[2];
  const float* w2  = (const float*)d_in[3];

  float* out = (float*)d_out;
  float* spk_out = out;                       // [15,250,126,126]
  float* pot_out = out + SPK_ELEMS;           // [15,250,126,126]
  float* win_out = out + 2 * SPK_ELEMS;       // [8,3]

  float* ws = (float*)d_ws;
  float* spk_in   = ws;                         // 7,372,800 f (29.5 MB)
  float* meta_val = ws + 7372800;               //   238,140
  int*   meta_f   = (int*)ws + 7610940;         //   238,140
  int*   winfeat  = (int*)ws + 7849080;         //    15,876
  float* cand_val = ws + 7864956;               //    15,876
  int*   cand_n   = (int*)ws + 7880832;         //    15,876

  // zero the padded spike map and the spk/pot outputs (winner scatter fills)
  hipMemsetAsync(spk_in, 0, 7372800 * sizeof(float), stream);
  hipMemsetAsync(out, 0, 2 * SPK_ELEMS * sizeof(float), stream);

  {
    dim3 g(18, 30, 15), b(128);
    conv1_v2<<<g, b, 0, stream>>>(inp, w1, spk_in);
  }
  {
    dim3 g(3, 126, 15), b(256);
    conv2_meta<<<g, b, 0, stream>>>(spk_in, w2, meta_val, meta_f);
  }
  inhibit2<<<(NPIX + 255) / 256, 256, 0, stream>>>(meta_val, meta_f, winfeat);
  winner_recompute<<<(NPIX + 255) / 256, 256, 0, stream>>>(
      winfeat, spk_in, w2, spk_out, pot_out, cand_val, cand_n);
  kwin_select<<<1, 1024, 0, stream>>>(cand_val, cand_n, winfeat, win_out);
}

// Round 7
// 1162.542 us; speedup vs baseline: 2.2405x; 1.1208x over previous
//
#include <hip/hip_runtime.h>
#include <limits.h>

#define T_STEPS 15
#define CIN     6
#define HIN     252
#define C1      30
#define SH      128
#define SW      128
#define C2      250
#define NPIX    15876          // 126*126
#define NTP     (T_STEPS*NPIX) // 238140
#define THR1    15.0f
#define THR2    10.0f
#define KWTA    8
#define SPK_ELEMS  59535000L   // 15*250*126*126

// ========== K0: weight transpose + ordered per-feature sums + argmax consts ==========
// blocks 0..269: wT[k][f] = w2[f][k] (f-major -> k-major, coalesced reads later)
// block 270: S[f] = ordered sum of w2[f][0..269] (bitwise = all-ones conv result),
//            Sthr = thresholded, consts = {max, argmax} with first-max semantics.
__global__ __launch_bounds__(256) void consts_k(
    const float* __restrict__ w2, float* __restrict__ wT,
    float* __restrict__ Sthr, float* __restrict__ consts) {
  const int f = threadIdx.x;
  if (blockIdx.x < 270) {
    int k = blockIdx.x;
    wT[k * 256 + f] = (f < C2) ? w2[(long)f * 270 + k] : 0.f;
    return;
  }
  __shared__ float sS[256];
  float S = 0.f;
  if (f < C2) {
    const float* wf = w2 + (long)f * 270;
    for (int k = 0; k < 270; ++k) S = fmaf(wf[k], 1.0f, S);  // == sequential add
  }
  float st = (f < C2 && S > THR2) ? S : 0.f;
  Sthr[f] = st;
  sS[f] = (f < C2) ? st : -1.f;
  __syncthreads();
  if (f == 0) {
    float bv = -1.f; int bf = 0;
    for (int i = 0; i < C2; ++i) { if (sS[i] > bv) { bv = sS[i]; bf = i; } }
    consts[0] = bv;                // thresholded max (>=0)
    ((int*)consts)[1] = bf;        // first-max feature
  }
}

// ========== K1: conv1 + fire + 2x2 pool(OR) + pad1, LDS-staged, all channels ==========
// grid (126 pooled rows, 15 t), 256 threads = 2 groups x 128 lanes (pw).
// Stage 6 input rows x 6 ic (full width, padded) once; each lane computes 15 channels.
__global__ __launch_bounds__(256) void conv1_v3(
    const int* __restrict__ inp, const float* __restrict__ w1,
    float* __restrict__ spk_in) {
  __shared__ float srow[6][6][256];   // [r][ic][col+2]
  const int ph = blockIdx.x, t = blockIdx.y;
  const int tid = threadIdx.x;
  for (int i = tid; i < 6 * 6 * 256; i += 256) {
    int col2 = i & 255, ric = i >> 8;
    int ic = ric % 6, r = ric / 6;
    int row = 2 * ph - 2 + r, col = col2 - 2;
    float v = 0.f;
    if (row >= 0 && row < HIN && col >= 0 && col < HIN)
      v = (float)inp[((long)(t * CIN + ic) * HIN + row) * HIN + col];
    srow[r][ic][col2] = v;
  }
  __syncthreads();
  const int g = tid >> 7, pw = tid & 127;
  float acc[15][4];
  #pragma unroll
  for (int c = 0; c < 15; ++c) { acc[c][0]=0.f; acc[c][1]=0.f; acc[c][2]=0.f; acc[c][3]=0.f; }
  for (int ic = 0; ic < CIN; ++ic) {           // ic ascending -> reference order
    float win[6][6];
    #pragma unroll
    for (int r = 0; r < 6; ++r)
      #pragma unroll
      for (int j = 0; j < 6; ++j)
        win[r][j] = srow[r][ic][(2 * pw + j) & 255];   // mask: lanes pw>=126 discarded
    for (int cc = 0; cc < 15; ++cc) {
      const float* wp = w1 + ((g * 15 + cc) * CIN + ic) * 25;  // uniform -> SGPR
      #pragma unroll
      for (int kh = 0; kh < 5; ++kh) {
        #pragma unroll
        for (int kw = 0; kw < 5; ++kw) {
          float wv = wp[kh * 5 + kw];
          acc[cc][0] = fmaf(wv, win[kh][kw],       acc[cc][0]);
          acc[cc][1] = fmaf(wv, win[kh][kw + 1],   acc[cc][1]);
          acc[cc][2] = fmaf(wv, win[kh + 1][kw],   acc[cc][2]);
          acc[cc][3] = fmaf(wv, win[kh + 1][kw + 1], acc[cc][3]);
        }
      }
    }
  }
  if (pw < 126) {
    #pragma unroll
    for (int cc = 0; cc < 15; ++cc) {
      int c = g * 15 + cc;
      bool fired = acc[cc][0] > THR1 || acc[cc][1] > THR1 ||
                   acc[cc][2] > THR1 || acc[cc][3] > THR1;
      spk_in[((long)(t * C1 + c) * SH + (ph + 1)) * SW + (pw + 1)] = fired ? 1.f : 0.f;
    }
  }
}

// ========== K2: classify pixels (all-ones window?) + constant meta ==========
__global__ __launch_bounds__(128) void classify(
    const float* __restrict__ spk_in, const float* __restrict__ consts,
    float* __restrict__ meta_val, int* __restrict__ meta_f,
    unsigned char* __restrict__ allones) {
  const int oh = blockIdx.x, t = blockIdx.y, ow = threadIdx.x;
  if (ow >= 126) return;
  const float* base = spk_in + (long)t * C1 * SH * SW;
  float prod = 1.f;
  for (int c = 0; c < C1; ++c) {
    const float* bp = base + (c * SH + oh) * SW + ow;
    #pragma unroll
    for (int kh = 0; kh < 3; ++kh)
      prod *= bp[kh * SW] * bp[kh * SW + 1] * bp[kh * SW + 2];
  }
  int tp = t * NPIX + oh * 126 + ow;
  bool ao = prod > 0.5f;                     // product of 0/1 values
  allones[tp] = ao ? 1 : 0;
  if (ao) { meta_val[tp] = consts[0]; meta_f[tp] = ((const int*)consts)[1]; }
}

// ========== K3: dense fallback for non-all-ones (t,p) — full 250-feature conv ==========
// grid MUST be 1024 blocks. Block b owns items {b + j*1024}; <=233 items/block.
__global__ __launch_bounds__(256) void dense_meta(
    const float* __restrict__ spk_in, const float* __restrict__ wT,
    const unsigned char* __restrict__ allones,
    float* __restrict__ meta_val, int* __restrict__ meta_f) {
  __shared__ int s_list[256];
  __shared__ int s_cnt;
  __shared__ float s_win[270][8];
  __shared__ unsigned long long s_part[4];
  const int tid = threadIdx.x;
  if (tid == 0) s_cnt = 0;
  __syncthreads();
  {
    int i = blockIdx.x + tid * 1024;
    if (i < NTP && !allones[i]) { int pos = atomicAdd(&s_cnt, 1); s_list[pos] = i; }
  }
  __syncthreads();
  const int cnt = s_cnt;
  for (int g = 0; g < cnt; g += 8) {
    int m = cnt - g; if (m > 8) m = 8;
    for (int j = tid; j < 270 * 8; j += 256) {
      int k = j >> 3, q = j & 7;
      float v = 0.f;
      if (q < m) {
        int tp = s_list[g + q];
        int t = tp / NPIX, p = tp % NPIX;
        int oh = p / 126, ow = p % 126;
        int c = k / 9, kh = (k % 9) / 3, kw = k % 3;
        v = spk_in[((long)(t * C1 + c) * SH + oh + kh) * SW + ow + kw];
      }
      s_win[k][q] = v;
    }
    __syncthreads();
    float acc[8];
    #pragma unroll
    for (int q = 0; q < 8; ++q) acc[q] = 0.f;
    for (int k = 0; k < 270; ++k) {          // k = (c,kh,kw) ascending = ref order
      float wv = wT[k * 256 + tid];          // coalesced
      #pragma unroll
      for (int q = 0; q < 8; ++q)
        acc[q] = fmaf(wv, s_win[k][q], acc[q]);
    }
    #pragma unroll
    for (int q = 0; q < 8; ++q) {
      unsigned long long key = 0;            // invalid lanes lose to any f<250
      if (tid < C2) {
        float v = acc[q] > THR2 ? acc[q] : 0.f;
        key = ((unsigned long long)__float_as_uint(v) << 8) | (unsigned)(255 - tid);
      }
      #pragma unroll
      for (int s = 1; s < 64; s <<= 1) {
        unsigned long long o = __shfl_xor(key, s, 64);
        if (o > key) key = o;
      }
      if ((tid & 63) == 0) s_part[tid >> 6] = key;
      __syncthreads();
      if (tid == 0 && q < m) {
        unsigned long long k0 = s_part[0];
        if (s_part[1] > k0) k0 = s_part[1];
        if (s_part[2] > k0) k0 = s_part[2];
        if (s_part[3] > k0) k0 = s_part[3];
        int tp = s_list[g + q];
        meta_val[tp] = __uint_as_float((unsigned)(k0 >> 8));
        meta_f[tp] = 255 - (int)(k0 & 255);
      }
      __syncthreads();
    }
  }
}

// ========== K4: per-pixel winner feature ==========
__global__ __launch_bounds__(256) void inhibit2(
    const float* __restrict__ meta_val, const int* __restrict__ meta_f,
    int* __restrict__ winfeat) {
  int p = blockIdx.x * 256 + threadIdx.x;
  if (p >= NPIX) return;
  int n = 0; bool last = false;
  #pragma unroll
  for (int t = 0; t < T_STEPS; ++t) {
    bool fr = meta_val[t * NPIX + p] > 0.f;
    n += fr ? 1 : 0;
    if (t == T_STEPS - 1) last = fr;
  }
  int e = T_STEPS - n;
  if (e > T_STEPS - 1) e = T_STEPS - 1;
  if (e < 0) e = 0;
  winfeat[p] = last ? meta_f[e * NPIX + p] : -1;
}

// ========== K5: winner columns -> output scatter + candidates ==========
__global__ __launch_bounds__(256) void winner_recomputeB(
    const int* __restrict__ winfeat, const unsigned char* __restrict__ allones,
    const float* __restrict__ Sthr, const float* __restrict__ spk_in,
    const float* __restrict__ w2, float* __restrict__ spk_out,
    float* __restrict__ pot_out, float* __restrict__ cand_val,
    int* __restrict__ cand_n) {
  int p = blockIdx.x * 256 + threadIdx.x;
  if (p >= NPIX) return;
  int w = winfeat[p];
  if (w < 0) { cand_val[p] = 0.f; cand_n[p] = 0; return; }
  const float sw = Sthr[w];
  const float* wb = w2 + (long)w * 270;
  int oh = p / 126, ow = p % 126;
  float pv[T_STEPS]; int n = 0;
  for (int t = 0; t < T_STEPS; ++t) {
    float pt;
    if (allones[t * NPIX + p]) {
      pt = sw;                               // bitwise = ordered dense sum, thresholded
    } else {
      float a = 0.f;
      for (int c = 0; c < C1; ++c) {
        const float* sb = spk_in + ((long)(t * C1 + c) * SH + oh) * SW + ow;
        #pragma unroll
        for (int kh = 0; kh < 3; ++kh)
          #pragma unroll
          for (int kw = 0; kw < 3; ++kw)
            a = fmaf(wb[c * 9 + kh * 3 + kw], sb[kh * SW + kw], a);
      }
      pt = a > THR2 ? a : 0.f;
    }
    pv[t] = pt;
    n += pt > 0.f ? 1 : 0;
    long o = ((long)t * C2 + w) * NPIX + p;
    pot_out[o] = pt;
    spk_out[o] = pt > 0.f ? 1.f : 0.f;
  }
  int e = T_STEPS - n; if (e > 14) e = 14; if (e < 0) e = 0;
  float cv = 0.f;
  #pragma unroll
  for (int t = 0; t < T_STEPS; ++t) if (t == e) cv = pv[t];   // static indexing
  cand_val[p] = cv;
  cand_n[p] = n;
}

// ========== K6: 8 rounds argmax + NMS (single block) ==========
__global__ __launch_bounds__(1024) void kwin_select(
    const float* __restrict__ cand_val, const int* __restrict__ cand_n,
    const int* __restrict__ winfeat, float* __restrict__ winners_out) {
  __shared__ float r_val[1024];
  __shared__ int   r_idx[1024];
  __shared__ unsigned char featrem[C2];
  __shared__ unsigned char rem[NPIX];
  __shared__ int s_rw, s_cw;
  const int tid = threadIdx.x;

  for (int i = tid; i < C2; i += 1024) featrem[i] = 0;
  for (int i = tid; i < NPIX; i += 1024) rem[i] = 0;

  float m = 0.f;
  for (int i = tid; i < NPIX; i += 1024) m = fmaxf(m, cand_val[i]);
  r_val[tid] = m;
  __syncthreads();
  for (int s = 512; s > 0; s >>= 1) {
    if (tid < s) r_val[tid] = fmaxf(r_val[tid], r_val[tid + s]);
    __syncthreads();
  }
  const float v = r_val[0] * (float)T_STEPS;
  __syncthreads();

  for (int round = 0; round < KWTA; ++round) {
    float bv = 0.f; int bi = INT_MAX;
    for (int p = tid; p < NPIX; p += 1024) {
      if (rem[p]) continue;
      int w = winfeat[p];
      if (w < 0 || featrem[w]) continue;
      float x = cand_val[p] + v;            // sequential n-term sum = reference bitwise
      int n = cand_n[p];
      float tot = 0.f;
      for (int q = 0; q < n; ++q) tot += x;
      int flat = w * NPIX + p;
      if (tot > bv || (tot == bv && flat < bi)) { bv = tot; bi = flat; }
    }
    r_val[tid] = bv; r_idx[tid] = bi;
    __syncthreads();
    for (int s = 512; s > 0; s >>= 1) {
      if (tid < s) {
        float ov = r_val[tid + s]; int oi = r_idx[tid + s];
        if (ov > r_val[tid] || (ov == r_val[tid] && oi < r_idx[tid])) {
          r_val[tid] = ov; r_idx[tid] = oi;
        }
      }
      __syncthreads();
    }
    if (tid == 0) {
      float mv = r_val[0]; int fi = r_idx[0];
      if (mv > 0.f && fi != INT_MAX) {
        int c = fi / NPIX; int p = fi % NPIX;
        int row = p / 126, col = p % 126;
        winners_out[round * 3 + 0] = (float)c;
        winners_out[round * 3 + 1] = (float)row;
        winners_out[round * 3 + 2] = (float)col;
        featrem[c] = 1;
        s_rw = row; s_cw = col;
      } else {
        winners_out[round * 3 + 0] = -1.f;
        winners_out[round * 3 + 1] = -1.f;
        winners_out[round * 3 + 2] = -1.f;
        s_rw = -10; s_cw = -10;
      }
    }
    __syncthreads();
    int rw = s_rw, cw = s_cw;
    if (rw >= 0) {
      for (int p = tid; p < NPIX; p += 1024) {
        int row = p / 126, col = p % 126;
        if (row >= rw - 1 && row <= rw + 1 && col >= cw - 1 && col <= cw + 1)
          rem[p] = 1;
      }
    }
    __syncthreads();
  }
}

// ---------------- launch ----------------
extern "C" void kernel_launch(void* const* d_in, const int* in_sizes, int n_in,
                              void* d_out, int out_size, void* d_ws, size_t ws_size,
                              hipStream_t stream) {
  const int*   inp = (const int*)d_in[0];
  const float* w1  = (const float*)d_in[2];
  const float* w2  = (const float*)d_in[3];

  float* out = (float*)d_out;
  float* spk_out = out;                       // [15,250,126,126]
  float* pot_out = out + SPK_ELEMS;           // [15,250,126,126]
  float* win_out = out + 2 * SPK_ELEMS;       // [8,3]

  float* ws = (float*)d_ws;
  float* spk_in   = ws;                               // 7,372,800
  float* meta_val = ws + 7372800;                     //   238,140
  int*   meta_f   = (int*)ws + 7610940;               //   238,140
  int*   winfeat  = (int*)ws + 7849080;               //    15,876
  float* cand_val = ws + 7864956;                     //    15,876
  int*   cand_n   = (int*)ws + 7880832;               //    15,876
  float* Sthr     = ws + 7896708;                     //       256
  float* consts   = ws + 7896964;                     //         4
  float* wT       = ws + 7896968;                     //    69,120 (270*256)
  unsigned char* allones = (unsigned char*)(ws + 7966088);  // 238,140 B
  // total ~32.1 MB of ws

  hipMemsetAsync(spk_in, 0, 7372800 * sizeof(float), stream);     // pad ring
  hipMemsetAsync(out, 0, 2 * SPK_ELEMS * sizeof(float), stream);  // scatter-fill

  consts_k<<<271, 256, 0, stream>>>(w2, wT, Sthr, consts);
  {
    dim3 g(126, 15);
    conv1_v3<<<g, 256, 0, stream>>>(inp, w1, spk_in);
  }
  {
    dim3 g(126, 15);
    classify<<<g, 128, 0, stream>>>(spk_in, consts, meta_val, meta_f, allones);
  }
  dense_meta<<<1024, 256, 0, stream>>>(spk_in, wT, allones, meta_val, meta_f);
  inhibit2<<<(NPIX + 255) / 256, 256, 0, stream>>>(meta_val, meta_f, winfeat);
  winner_recomputeB<<<(NPIX + 255) / 256, 256, 0, stream>>>(
      winfeat, allones, Sthr, spk_in, w2, spk_out, pot_out, cand_val, cand_n);
  kwin_select<<<1, 1024, 0, stream>>>(cand_val, cand_n, winfeat, win_out);
}

// Round 9
// 810.987 us; speedup vs baseline: 3.2118x; 1.4335x over previous
//
#include <hip/hip_runtime.h>
#include <limits.h>

#define T_STEPS 15
#define CIN     6
#define HIN     252
#define C1      30
#define SH      128
#define SW      128
#define C2      250
#define NPIX    15876          // 126*126
#define NTP     (T_STEPS*NPIX) // 238140
#define THR1    15.0f
#define THR2    10.0f
#define KWTA    8
#define SPK_ELEMS  59535000L   // 15*250*126*126

// ========== K0: weight transpose + ordered per-feature sums + argmax consts ==========
__global__ __launch_bounds__(256) void consts_k(
    const float* __restrict__ w2, float* __restrict__ wT,
    float* __restrict__ Sthr, float* __restrict__ consts) {
  const int f = threadIdx.x;
  if (blockIdx.x < 270) {
    int k = blockIdx.x;
    wT[k * 256 + f] = (f < C2) ? w2[(long)f * 270 + k] : 0.f;
    return;
  }
  __shared__ float sS[256];
  float S = 0.f;
  if (f < C2) {
    const float* wf = w2 + (long)f * 270;
    for (int k = 0; k < 270; ++k) S = fmaf(wf[k], 1.0f, S);  // == sequential add
  }
  float st = (f < C2 && S > THR2) ? S : 0.f;
  Sthr[f] = st;
  sS[f] = (f < C2) ? st : -1.f;
  __syncthreads();
  if (f == 0) {
    float bv = -1.f; int bf = 0;
    for (int i = 0; i < C2; ++i) { if (sS[i] > bv) { bv = sS[i]; bf = i; } }
    consts[0] = bv;                // thresholded max (>=0)
    ((int*)consts)[1] = bf;        // first-max feature
  }
}

// ========== K1: conv1 + fire + 2x2 pool(OR) + pad1 — low-VGPR, 6KB LDS ==========
// grid (126 ph, 6 channel-groups of 5, 15 t), block 128 lanes (pw).
// Per ic: stage 6 padded rows (256 cols) in LDS; stream rows into 4 accumulators
// per channel. Order per output: ic asc, kh asc (rr), kw asc — bitwise = reference.
#define G1 5
__global__ __launch_bounds__(128, 6) void conv1_v4(
    const int* __restrict__ inp, const float* __restrict__ w1,
    float* __restrict__ spk_in) {
  __shared__ float srow[6][256];      // [rr][padded col]
  const int ph = blockIdx.x;
  const int cg = blockIdx.y;
  const int t  = blockIdx.z;
  const int pw = threadIdx.x;         // 0..127 (126 used)

  float acc[G1][4];
  #pragma unroll
  for (int cc = 0; cc < G1; ++cc) {
    acc[cc][0] = 0.f; acc[cc][1] = 0.f; acc[cc][2] = 0.f; acc[cc][3] = 0.f;
  }

  for (int ic = 0; ic < CIN; ++ic) {
    __syncthreads();                  // protect previous ic's rows
    for (int i = pw; i < 6 * 256; i += 128) {
      int rr = i >> 8, col = i & 255;
      int row = 2 * ph - 2 + rr, in_col = col - 2;
      float v = 0.f;
      if (row >= 0 && row < HIN && in_col >= 0 && in_col < HIN)
        v = (float)inp[((long)(t * CIN + ic) * HIN + row) * HIN + in_col];
      srow[rr][col] = v;
    }
    __syncthreads();

    #pragma unroll
    for (int rr = 0; rr < 6; ++rr) {
      float row6[6];
      #pragma unroll
      for (int j = 0; j < 6; ++j)
        row6[j] = srow[rr][(2 * pw + j) & 255];   // mask: lanes pw>=126 discarded
      #pragma unroll
      for (int cc = 0; cc < G1; ++cc) {
        const int c = cg * G1 + cc;
        const float* wp = w1 + ((c * CIN) + ic) * 25;   // wave-uniform -> s_load
        if (rr < 5) {                 // kh = rr for output row 2ph
          #pragma unroll
          for (int kw = 0; kw < 5; ++kw) {
            float wv = wp[rr * 5 + kw];
            acc[cc][0] = fmaf(wv, row6[kw],     acc[cc][0]);
            acc[cc][1] = fmaf(wv, row6[kw + 1], acc[cc][1]);
          }
        }
        if (rr >= 1) {                // kh = rr-1 for output row 2ph+1
          #pragma unroll
          for (int kw = 0; kw < 5; ++kw) {
            float wv = wp[(rr - 1) * 5 + kw];
            acc[cc][2] = fmaf(wv, row6[kw],     acc[cc][2]);
            acc[cc][3] = fmaf(wv, row6[kw + 1], acc[cc][3]);
          }
        }
      }
    }
  }
  if (pw < 126) {
    #pragma unroll
    for (int cc = 0; cc < G1; ++cc) {
      int c = cg * G1 + cc;
      bool fired = acc[cc][0] > THR1 || acc[cc][1] > THR1 ||
                   acc[cc][2] > THR1 || acc[cc][3] > THR1;
      spk_in[((long)(t * C1 + c) * SH + (ph + 1)) * SW + (pw + 1)] = fired ? 1.f : 0.f;
    }
  }
}

// ========== K2: classify pixels (all-ones window?) + constant meta ==========
__global__ __launch_bounds__(128) void classify(
    const float* __restrict__ spk_in, const float* __restrict__ consts,
    float* __restrict__ meta_val, int* __restrict__ meta_f,
    unsigned char* __restrict__ allones) {
  const int oh = blockIdx.x, t = blockIdx.y, ow = threadIdx.x;
  if (ow >= 126) return;
  const float* base = spk_in + (long)t * C1 * SH * SW;
  float prod = 1.f;
  for (int c = 0; c < C1; ++c) {
    const float* bp = base + (c * SH + oh) * SW + ow;
    #pragma unroll
    for (int kh = 0; kh < 3; ++kh)
      prod *= bp[kh * SW] * bp[kh * SW + 1] * bp[kh * SW + 2];
  }
  int tp = t * NPIX + oh * 126 + ow;
  bool ao = prod > 0.5f;                     // product of 0/1 values
  allones[tp] = ao ? 1 : 0;
  if (ao) { meta_val[tp] = consts[0]; meta_f[tp] = ((const int*)consts)[1]; }
}

// ========== K3: dense fallback for non-all-ones (t,p) — full 250-feature conv ==========
// grid MUST be 1024 blocks. Block b owns items {b + j*1024}; <=233 items/block.
__global__ __launch_bounds__(256) void dense_meta(
    const float* __restrict__ spk_in, const float* __restrict__ wT,
    const unsigned char* __restrict__ allones,
    float* __restrict__ meta_val, int* __restrict__ meta_f) {
  __shared__ int s_list[256];
  __shared__ int s_cnt;
  __shared__ float s_win[270][8];
  __shared__ unsigned long long s_part[4];
  const int tid = threadIdx.x;
  if (tid == 0) s_cnt = 0;
  __syncthreads();
  {
    int i = blockIdx.x + tid * 1024;
    if (i < NTP && !allones[i]) { int pos = atomicAdd(&s_cnt, 1); s_list[pos] = i; }
  }
  __syncthreads();
  const int cnt = s_cnt;
  for (int g = 0; g < cnt; g += 8) {
    int m = cnt - g; if (m > 8) m = 8;
    for (int j = tid; j < 270 * 8; j += 256) {
      int k = j >> 3, q = j & 7;
      float v = 0.f;
      if (q < m) {
        int tp = s_list[g + q];
        int t = tp / NPIX, p = tp % NPIX;
        int oh = p / 126, ow = p % 126;
        int c = k / 9, kh = (k % 9) / 3, kw = k % 3;
        v = spk_in[((long)(t * C1 + c) * SH + oh + kh) * SW + ow + kw];
      }
      s_win[k][q] = v;
    }
    __syncthreads();
    float acc[8];
    #pragma unroll
    for (int q = 0; q < 8; ++q) acc[q] = 0.f;
    for (int k = 0; k < 270; ++k) {          // k = (c,kh,kw) ascending = ref order
      float wv = wT[k * 256 + tid];          // coalesced
      #pragma unroll
      for (int q = 0; q < 8; ++q)
        acc[q] = fmaf(wv, s_win[k][q], acc[q]);
    }
    #pragma unroll
    for (int q = 0; q < 8; ++q) {
      unsigned long long key = 0;            // invalid lanes lose to any f<250
      if (tid < C2) {
        float v = acc[q] > THR2 ? acc[q] : 0.f;
        key = ((unsigned long long)__float_as_uint(v) << 8) | (unsigned)(255 - tid);
      }
      #pragma unroll
      for (int s = 1; s < 64; s <<= 1) {
        unsigned long long o = __shfl_xor(key, s, 64);
        if (o > key) key = o;
      }
      if ((tid & 63) == 0) s_part[tid >> 6] = key;
      __syncthreads();
      if (tid == 0 && q < m) {
        unsigned long long k0 = s_part[0];
        if (s_part[1] > k0) k0 = s_part[1];
        if (s_part[2] > k0) k0 = s_part[2];
        if (s_part[3] > k0) k0 = s_part[3];
        int tp = s_list[g + q];
        meta_val[tp] = __uint_as_float((unsigned)(k0 >> 8));
        meta_f[tp] = 255 - (int)(k0 & 255);
      }
      __syncthreads();
    }
  }
}

// ========== K4: per-pixel winner feature ==========
__global__ __launch_bounds__(256) void inhibit2(
    const float* __restrict__ meta_val, const int* __restrict__ meta_f,
    int* __restrict__ winfeat) {
  int p = blockIdx.x * 256 + threadIdx.x;
  if (p >= NPIX) return;
  int n = 0; bool last = false;
  #pragma unroll
  for (int t = 0; t < T_STEPS; ++t) {
    bool fr = meta_val[t * NPIX + p] > 0.f;
    n += fr ? 1 : 0;
    if (t == T_STEPS - 1) last = fr;
  }
  int e = T_STEPS - n;
  if (e > T_STEPS - 1) e = T_STEPS - 1;
  if (e < 0) e = 0;
  winfeat[p] = last ? meta_f[e * NPIX + p] : -1;
}

// ========== K5a: per-(t,p) winner potential + output scatter ==========
// pvbuf reuses the dead meta_val buffer. 931 blocks x 256 covers NTP.
__global__ __launch_bounds__(256) void winner_pv(
    const int* __restrict__ winfeat, const unsigned char* __restrict__ allones,
    const float* __restrict__ Sthr, const float* __restrict__ spk_in,
    const float* __restrict__ w2, float* __restrict__ spk_out,
    float* __restrict__ pot_out, float* __restrict__ pvbuf) {
  int tp = blockIdx.x * 256 + threadIdx.x;
  if (tp >= NTP) return;
  int t = tp / NPIX, p = tp % NPIX;
  int w = winfeat[p];
  if (w < 0) { pvbuf[tp] = 0.f; return; }
  float pt;
  if (allones[tp]) {
    pt = Sthr[w];                            // bitwise = ordered dense sum, thresholded
  } else {
    int oh = p / 126, ow = p % 126;
    const float* wb = w2 + (long)w * 270;
    float a = 0.f;
    for (int c = 0; c < C1; ++c) {
      const float* sb = spk_in + ((long)(t * C1 + c) * SH + oh) * SW + ow;
      #pragma unroll
      for (int kh = 0; kh < 3; ++kh)
        #pragma unroll
        for (int kw = 0; kw < 3; ++kw)
          a = fmaf(wb[c * 9 + kh * 3 + kw], sb[kh * SW + kw], a);
    }
    pt = a > THR2 ? a : 0.f;
  }
  pvbuf[tp] = pt;
  long o = ((long)t * C2 + w) * NPIX + p;
  pot_out[o] = pt;
  spk_out[o] = pt > 0.f ? 1.f : 0.f;
}

// ========== K5b: per-pixel candidate (n, value at earliest) ==========
__global__ __launch_bounds__(256) void cand_k(
    const int* __restrict__ winfeat, const float* __restrict__ pvbuf,
    float* __restrict__ cand_val, int* __restrict__ cand_n) {
  int p = blockIdx.x * 256 + threadIdx.x;
  if (p >= NPIX) return;
  int w = winfeat[p];
  if (w < 0) { cand_val[p] = 0.f; cand_n[p] = 0; return; }
  float pv[T_STEPS]; int n = 0;
  #pragma unroll
  for (int t = 0; t < T_STEPS; ++t) {
    float v = pvbuf[t * NPIX + p];           // coalesced per t
    pv[t] = v;
    n += v > 0.f ? 1 : 0;
  }
  int e = T_STEPS - n; if (e > 14) e = 14; if (e < 0) e = 0;
  float cv = 0.f;
  #pragma unroll
  for (int t = 0; t < T_STEPS; ++t) if (t == e) cv = pv[t];   // static indexing
  cand_val[p] = cv;
  cand_n[p] = n;
}

// ========== K6: 8 rounds argmax + NMS (single block) ==========
__global__ __launch_bounds__(1024) void kwin_select(
    const float* __restrict__ cand_val, const int* __restrict__ cand_n,
    const int* __restrict__ winfeat, float* __restrict__ winners_out) {
  __shared__ float r_val[1024];
  __shared__ int   r_idx[1024];
  __shared__ unsigned char featrem[C2];
  __shared__ unsigned char rem[NPIX];
  __shared__ int s_rw, s_cw;
  const int tid = threadIdx.x;

  for (int i = tid; i < C2; i += 1024) featrem[i] = 0;
  for (int i = tid; i < NPIX; i += 1024) rem[i] = 0;

  float m = 0.f;
  for (int i = tid; i < NPIX; i += 1024) m = fmaxf(m, cand_val[i]);
  r_val[tid] = m;
  __syncthreads();
  for (int s = 512; s > 0; s >>= 1) {
    if (tid < s) r_val[tid] = fmaxf(r_val[tid], r_val[tid + s]);
    __syncthreads();
  }
  const float v = r_val[0] * (float)T_STEPS;
  __syncthreads();

  for (int round = 0; round < KWTA; ++round) {
    float bv = 0.f; int bi = INT_MAX;
    for (int p = tid; p < NPIX; p += 1024) {
      if (rem[p]) continue;
      int w = winfeat[p];
      if (w < 0 || featrem[w]) continue;
      float x = cand_val[p] + v;            // sequential n-term sum = reference bitwise
      int n = cand_n[p];
      float tot = 0.f;
      for (int q = 0; q < n; ++q) tot += x;
      int flat = w * NPIX + p;
      if (tot > bv || (tot == bv && flat < bi)) { bv = tot; bi = flat; }
    }
    r_val[tid] = bv; r_idx[tid] = bi;
    __syncthreads();
    for (int s = 512; s > 0; s >>= 1) {
      if (tid < s) {
        float ov = r_val[tid + s]; int oi = r_idx[tid + s];
        if (ov > r_val[tid] || (ov == r_val[tid] && oi < r_idx[tid])) {
          r_val[tid] = ov; r_idx[tid] = oi;
        }
      }
      __syncthreads();
    }
    if (tid == 0) {
      float mv = r_val[0]; int fi = r_idx[0];
      if (mv > 0.f && fi != INT_MAX) {
        int c = fi / NPIX; int p = fi % NPIX;
        int row = p / 126, col = p % 126;
        winners_out[round * 3 + 0] = (float)c;
        winners_out[round * 3 + 1] = (float)row;
        winners_out[round * 3 + 2] = (float)col;
        featrem[c] = 1;
        s_rw = row; s_cw = col;
      } else {
        winners_out[round * 3 + 0] = -1.f;
        winners_out[round * 3 + 1] = -1.f;
        winners_out[round * 3 + 2] = -1.f;
        s_rw = -10; s_cw = -10;
      }
    }
    __syncthreads();
    int rw = s_rw, cw = s_cw;
    if (rw >= 0) {
      for (int p = tid; p < NPIX; p += 1024) {
        int row = p / 126, col = p % 126;
        if (row >= rw - 1 && row <= rw + 1 && col >= cw - 1 && col <= cw + 1)
          rem[p] = 1;
      }
    }
    __syncthreads();
  }
}

// ---------------- launch ----------------
extern "C" void kernel_launch(void* const* d_in, const int* in_sizes, int n_in,
                              void* d_out, int out_size, void* d_ws, size_t ws_size,
                              hipStream_t stream) {
  const int*   inp = (const int*)d_in[0];
  const float* w1  = (const float*)d_in[2];
  const float* w2  = (const float*)d_in[3];

  float* out = (float*)d_out;
  float* spk_out = out;                       // [15,250,126,126]
  float* pot_out = out + SPK_ELEMS;           // [15,250,126,126]
  float* win_out = out + 2 * SPK_ELEMS;       // [8,3]

  float* ws = (float*)d_ws;
  float* spk_in   = ws;                               // 7,372,800
  float* meta_val = ws + 7372800;                     //   238,140 (reused as pvbuf)
  int*   meta_f   = (int*)ws + 7610940;               //   238,140
  int*   winfeat  = (int*)ws + 7849080;               //    15,876
  float* cand_val = ws + 7864956;                     //    15,876
  int*   cand_n   = (int*)ws + 7880832;               //    15,876
  float* Sthr     = ws + 7896708;                     //       256
  float* consts   = ws + 7896964;                     //         4
  float* wT       = ws + 7896968;                     //    69,120 (270*256)
  unsigned char* allones = (unsigned char*)(ws + 7966088);  // 238,140 B

  hipMemsetAsync(spk_in, 0, 7372800 * sizeof(float), stream);     // pad ring
  hipMemsetAsync(out, 0, 2 * SPK_ELEMS * sizeof(float), stream);  // scatter-fill

  consts_k<<<271, 256, 0, stream>>>(w2, wT, Sthr, consts);
  {
    dim3 g(126, 6, 15);
    conv1_v4<<<g, 128, 0, stream>>>(inp, w1, spk_in);
  }
  {
    dim3 g(126, 15);
    classify<<<g, 128, 0, stream>>>(spk_in, consts, meta_val, meta_f, allones);
  }
  dense_meta<<<1024, 256, 0, stream>>>(spk_in, wT, allones, meta_val, meta_f);
  inhibit2<<<(NPIX + 255) / 256, 256, 0, stream>>>(meta_val, meta_f, winfeat);
  winner_pv<<<(NTP + 255) / 256, 256, 0, stream>>>(
      winfeat, allones, Sthr, spk_in, w2, spk_out, pot_out, meta_val /*pvbuf*/);
  cand_k<<<(NPIX + 255) / 256, 256, 0, stream>>>(winfeat, meta_val, cand_val, cand_n);
  kwin_select<<<1, 1024, 0, stream>>>(cand_val, cand_n, winfeat, win_out);
}

// Round 10
// 795.570 us; speedup vs baseline: 3.2740x; 1.0194x over previous
//
#include <hip/hip_runtime.h>
#include <limits.h>

#define T_STEPS 15
#define CIN     6
#define HIN     252
#define C1      30
#define SH      128
#define SW      128
#define C2      250
#define NPIX    15876          // 126*126
#define NTP     (T_STEPS*NPIX) // 238140
#define THR1    15.0f
#define THR2    10.0f
#define KWTA    8
#define SPK_ELEMS  59535000L   // 15*250*126*126

// ========== K0: weight transpose + ordered per-feature sums + argmax consts ==========
__global__ __launch_bounds__(256) void consts_k(
    const float* __restrict__ w2, float* __restrict__ wT,
    float* __restrict__ Sthr, float* __restrict__ consts) {
  const int f = threadIdx.x;
  if (blockIdx.x < 270) {
    int k = blockIdx.x;
    wT[k * 256 + f] = (f < C2) ? w2[(long)f * 270 + k] : 0.f;
    return;
  }
  __shared__ float sS[256];
  float S = 0.f;
  if (f < C2) {
    const float* wf = w2 + (long)f * 270;
    for (int k = 0; k < 270; ++k) S = fmaf(wf[k], 1.0f, S);  // == sequential add
  }
  float st = (f < C2 && S > THR2) ? S : 0.f;
  Sthr[f] = st;
  sS[f] = (f < C2) ? st : -1.f;
  __syncthreads();
  if (f == 0) {
    float bv = -1.f; int bf = 0;
    for (int i = 0; i < C2; ++i) { if (sS[i] > bv) { bv = sS[i]; bf = i; } }
    consts[0] = bv;                // thresholded max (>=0)
    ((int*)consts)[1] = bf;        // first-max feature
  }
}

// ========== K1: conv1 + fire + pool + pad1, float map + 128-bit row bitmasks ==========
#define G1 5
__global__ __launch_bounds__(128, 6) void conv1_v4b(
    const int* __restrict__ inp, const float* __restrict__ w1,
    float* __restrict__ spk_in, unsigned long long* __restrict__ bitm) {
  __shared__ float srow[6][256];      // [rr][padded col]
  __shared__ unsigned long long s_bal[2][G1];
  const int ph = blockIdx.x;
  const int cg = blockIdx.y;
  const int t  = blockIdx.z;
  const int pw = threadIdx.x;         // 0..127 (126 used)

  float acc[G1][4];
  #pragma unroll
  for (int cc = 0; cc < G1; ++cc) {
    acc[cc][0] = 0.f; acc[cc][1] = 0.f; acc[cc][2] = 0.f; acc[cc][3] = 0.f;
  }

  for (int ic = 0; ic < CIN; ++ic) {
    __syncthreads();                  // protect previous ic's rows
    for (int i = pw; i < 6 * 256; i += 128) {
      int rr = i >> 8, col = i & 255;
      int row = 2 * ph - 2 + rr, in_col = col - 2;
      float v = 0.f;
      if (row >= 0 && row < HIN && in_col >= 0 && in_col < HIN)
        v = (float)inp[((long)(t * CIN + ic) * HIN + row) * HIN + in_col];
      srow[rr][col] = v;
    }
    __syncthreads();

    #pragma unroll
    for (int rr = 0; rr < 6; ++rr) {
      float row6[6];
      #pragma unroll
      for (int j = 0; j < 6; ++j)
        row6[j] = srow[rr][(2 * pw + j) & 255];   // mask: lanes pw>=126 discarded
      #pragma unroll
      for (int cc = 0; cc < G1; ++cc) {
        const int c = cg * G1 + cc;
        const float* wp = w1 + ((c * CIN) + ic) * 25;   // wave-uniform -> s_load
        if (rr < 5) {                 // kh = rr for output row 2ph
          #pragma unroll
          for (int kw = 0; kw < 5; ++kw) {
            float wv = wp[rr * 5 + kw];
            acc[cc][0] = fmaf(wv, row6[kw],     acc[cc][0]);
            acc[cc][1] = fmaf(wv, row6[kw + 1], acc[cc][1]);
          }
        }
        if (rr >= 1) {                // kh = rr-1 for output row 2ph+1
          #pragma unroll
          for (int kw = 0; kw < 5; ++kw) {
            float wv = wp[(rr - 1) * 5 + kw];
            acc[cc][2] = fmaf(wv, row6[kw],     acc[cc][2]);
            acc[cc][3] = fmaf(wv, row6[kw + 1], acc[cc][3]);
          }
        }
      }
    }
  }
  unsigned fbits = 0;
  #pragma unroll
  for (int cc = 0; cc < G1; ++cc) {
    bool fired = (pw < 126) && (acc[cc][0] > THR1 || acc[cc][1] > THR1 ||
                                acc[cc][2] > THR1 || acc[cc][3] > THR1);
    if (fired) fbits |= 1u << cc;
    if (pw < 126) {
      int c = cg * G1 + cc;
      spk_in[((long)(t * C1 + c) * SH + (ph + 1)) * SW + (pw + 1)] = fired ? 1.f : 0.f;
    }
  }
  // 128-bit bitmask per (t,c,padded row): bit col = spike (cols 1..126)
  #pragma unroll
  for (int cc = 0; cc < G1; ++cc) {
    unsigned long long b = __ballot((fbits >> cc) & 1);
    if ((pw & 63) == 0) s_bal[pw >> 6][cc] = b;
  }
  __syncthreads();
  if (pw < G1) {
    unsigned long long b0 = s_bal[0][pw], b1 = s_bal[1][pw];
    unsigned long long w0 = b0 << 1;
    unsigned long long w1 = (b1 << 1) | (b0 >> 63);
    int c = cg * G1 + pw;
    unsigned long long* bp = bitm + 2 * (((long)(t * C1 + c)) * SH + (ph + 1));
    bp[0] = w0; bp[1] = w1;
  }
}

// ========== K2: classify via bitmasks (all-ones window?) + constant meta ==========
__global__ __launch_bounds__(128) void classify2(
    const unsigned long long* __restrict__ bitm, const float* __restrict__ consts,
    float* __restrict__ meta_val, int* __restrict__ meta_f,
    unsigned char* __restrict__ allones) {
  const int oh = blockIdx.x, t = blockIdx.y, ow = threadIdx.x;
  unsigned long long lo = ~0ull, hi = ~0ull;
  for (int c = 0; c < C1; ++c) {
    const unsigned long long* bp = bitm + 2 * (((long)(t * C1 + c)) * SH + oh);
    lo &= bp[0] & bp[2] & bp[4];     // rows oh, oh+1, oh+2
    hi &= bp[1] & bp[3] & bp[5];
  }
  if (ow >= 126) return;
  unsigned long long x = (ow < 64)
      ? ((lo >> ow) | (ow ? (hi << (64 - ow)) : 0ull))
      : (hi >> (ow - 64));
  bool ao = (x & 7ull) == 7ull;      // cols ow, ow+1, ow+2 all ones across 30 ch
  int tp = t * NPIX + oh * 126 + ow;
  allones[tp] = ao ? 1 : 0;
  if (ao) { meta_val[tp] = consts[0]; meta_f[tp] = ((const int*)consts)[1]; }
}

// ========== K3: dense fallback for non-all-ones (t,p) — full 250-feature conv ==========
// grid MUST be 1024 blocks. Block b owns items {b + j*1024}; <=233 items/block.
__global__ __launch_bounds__(256) void dense_meta(
    const float* __restrict__ spk_in, const float* __restrict__ wT,
    const unsigned char* __restrict__ allones,
    float* __restrict__ meta_val, int* __restrict__ meta_f) {
  __shared__ int s_list[256];
  __shared__ int s_cnt;
  __shared__ float s_win[270][8];
  __shared__ unsigned long long s_part[4];
  const int tid = threadIdx.x;
  if (tid == 0) s_cnt = 0;
  __syncthreads();
  {
    int i = blockIdx.x + tid * 1024;
    if (i < NTP && !allones[i]) { int pos = atomicAdd(&s_cnt, 1); s_list[pos] = i; }
  }
  __syncthreads();
  const int cnt = s_cnt;
  for (int g = 0; g < cnt; g += 8) {
    int m = cnt - g; if (m > 8) m = 8;
    for (int j = tid; j < 270 * 8; j += 256) {
      int k = j >> 3, q = j & 7;
      float v = 0.f;
      if (q < m) {
        int tp = s_list[g + q];
        int t = tp / NPIX, p = tp % NPIX;
        int oh = p / 126, ow = p % 126;
        int c = k / 9, kh = (k % 9) / 3, kw = k % 3;
        v = spk_in[((long)(t * C1 + c) * SH + oh + kh) * SW + ow + kw];
      }
      s_win[k][q] = v;
    }
    __syncthreads();
    float acc[8];
    #pragma unroll
    for (int q = 0; q < 8; ++q) acc[q] = 0.f;
    for (int k = 0; k < 270; ++k) {          // k = (c,kh,kw) ascending = ref order
      float wv = wT[k * 256 + tid];          // coalesced
      #pragma unroll
      for (int q = 0; q < 8; ++q)
        acc[q] = fmaf(wv, s_win[k][q], acc[q]);
    }
    #pragma unroll
    for (int q = 0; q < 8; ++q) {
      unsigned long long key = 0;            // invalid lanes lose to any f<250
      if (tid < C2) {
        float v = acc[q] > THR2 ? acc[q] : 0.f;
        key = ((unsigned long long)__float_as_uint(v) << 8) | (unsigned)(255 - tid);
      }
      #pragma unroll
      for (int s = 1; s < 64; s <<= 1) {
        unsigned long long o = __shfl_xor(key, s, 64);
        if (o > key) key = o;
      }
      if ((tid & 63) == 0) s_part[tid >> 6] = key;
      __syncthreads();
      if (tid == 0 && q < m) {
        unsigned long long k0 = s_part[0];
        if (s_part[1] > k0) k0 = s_part[1];
        if (s_part[2] > k0) k0 = s_part[2];
        if (s_part[3] > k0) k0 = s_part[3];
        int tp = s_list[g + q];
        meta_val[tp] = __uint_as_float((unsigned)(k0 >> 8));
        meta_f[tp] = 255 - (int)(k0 & 255);
      }
      __syncthreads();
    }
  }
}

// ========== K4: per-pixel winner feature ==========
__global__ __launch_bounds__(256) void inhibit2(
    const float* __restrict__ meta_val, const int* __restrict__ meta_f,
    int* __restrict__ winfeat) {
  int p = blockIdx.x * 256 + threadIdx.x;
  if (p >= NPIX) return;
  int n = 0; bool last = false;
  #pragma unroll
  for (int t = 0; t < T_STEPS; ++t) {
    bool fr = meta_val[t * NPIX + p] > 0.f;
    n += fr ? 1 : 0;
    if (t == T_STEPS - 1) last = fr;
  }
  int e = T_STEPS - n;
  if (e > T_STEPS - 1) e = T_STEPS - 1;
  if (e < 0) e = 0;
  winfeat[p] = last ? meta_f[e * NPIX + p] : -1;
}

// ========== K5a: per-(t,p) winner potential + output scatter ==========
__global__ __launch_bounds__(256) void winner_pv(
    const int* __restrict__ winfeat, const unsigned char* __restrict__ allones,
    const float* __restrict__ Sthr, const float* __restrict__ spk_in,
    const float* __restrict__ w2, float* __restrict__ spk_out,
    float* __restrict__ pot_out, float* __restrict__ pvbuf) {
  int tp = blockIdx.x * 256 + threadIdx.x;
  if (tp >= NTP) return;
  int t = tp / NPIX, p = tp % NPIX;
  int w = winfeat[p];
  if (w < 0) { pvbuf[tp] = 0.f; return; }
  float pt;
  if (allones[tp]) {
    pt = Sthr[w];                            // bitwise = ordered dense sum, thresholded
  } else {
    int oh = p / 126, ow = p % 126;
    const float* wb = w2 + (long)w * 270;
    float a = 0.f;
    for (int c = 0; c < C1; ++c) {
      const float* sb = spk_in + ((long)(t * C1 + c) * SH + oh) * SW + ow;
      #pragma unroll
      for (int kh = 0; kh < 3; ++kh)
        #pragma unroll
        for (int kw = 0; kw < 3; ++kw)
          a = fmaf(wb[c * 9 + kh * 3 + kw], sb[kh * SW + kw], a);
    }
    pt = a > THR2 ? a : 0.f;
  }
  pvbuf[tp] = pt;
  long o = ((long)t * C2 + w) * NPIX + p;
  pot_out[o] = pt;
  spk_out[o] = pt > 0.f ? 1.f : 0.f;
}

// ========== K5b: per-pixel candidate (n, value at earliest) ==========
__global__ __launch_bounds__(256) void cand_k(
    const int* __restrict__ winfeat, const float* __restrict__ pvbuf,
    float* __restrict__ cand_val, int* __restrict__ cand_n) {
  int p = blockIdx.x * 256 + threadIdx.x;
  if (p >= NPIX) return;
  int w = winfeat[p];
  if (w < 0) { cand_val[p] = 0.f; cand_n[p] = 0; return; }
  float pv[T_STEPS]; int n = 0;
  #pragma unroll
  for (int t = 0; t < T_STEPS; ++t) {
    float v = pvbuf[t * NPIX + p];
    pv[t] = v;
    n += v > 0.f ? 1 : 0;
  }
  int e = T_STEPS - n; if (e > 14) e = 14; if (e < 0) e = 0;
  float cv = 0.f;
  #pragma unroll
  for (int t = 0; t < T_STEPS; ++t) if (t == e) cv = pv[t];   // static indexing
  cand_val[p] = cv;
  cand_n[p] = n;
}

// ========== K6: LDS-resident 8-round argmax + NMS (single block) ==========
__global__ __launch_bounds__(1024) void kwin_select2(
    const float* __restrict__ cand_val, const int* __restrict__ cand_n,
    const int* __restrict__ winfeat, float* __restrict__ winners_out) {
  __shared__ float s_tot[NPIX];              // 63.5 KB
  __shared__ unsigned char s_w[NPIX];        // 15.9 KB (255 = none)
  __shared__ unsigned char s_rem[NPIX];      // 15.9 KB
  __shared__ unsigned char s_fr[256];
  __shared__ unsigned long long s_part[16];
  __shared__ float s_max[16];
  __shared__ int s_sel;
  const int tid = threadIdx.x;
  const int wid = tid >> 6, lane = tid & 63;

  if (tid < 256) s_fr[tid] = 0;

  float m = 0.f;
  for (int p = tid; p < NPIX; p += 1024) {
    int w = winfeat[p];
    s_w[p] = (w < 0) ? 255 : (unsigned char)w;
    s_rem[p] = 0;
    float cv = cand_val[p];
    s_tot[p] = cv;                           // temp: cv
    m = fmaxf(m, cv);
  }
  #pragma unroll
  for (int s = 1; s < 64; s <<= 1) m = fmaxf(m, __shfl_xor(m, s, 64));
  if (lane == 0) s_max[wid] = m;
  __syncthreads();
  if (tid == 0) {
    float mm = s_max[0];
    for (int i = 1; i < 16; ++i) mm = fmaxf(mm, s_max[i]);
    s_max[0] = mm * (float)T_STEPS;          // v = T * max(trunc)
  }
  __syncthreads();
  const float v = s_max[0];
  for (int p = tid; p < NPIX; p += 1024) {
    float x = s_tot[p] + v;
    int n = cand_n[p];
    float tot = 0.f;
    for (int q = 0; q < n; ++q) tot += x;    // sequential n-term sum = ref bitwise
    s_tot[p] = tot;
  }
  __syncthreads();

  for (int round = 0; round < KWTA; ++round) {
    unsigned long long best = 0;
    for (int p = tid; p < NPIX; p += 1024) {
      unsigned char w = s_w[p];
      if (w == 255 || s_rem[p] || s_fr[w]) continue;
      unsigned long long flat = (unsigned long long)w * NPIX + (unsigned)p; // <2^22
      unsigned long long key =
          ((unsigned long long)__float_as_uint(s_tot[p]) << 25) | (0x1FFFFFFull - flat);
      if (key > best) best = key;            // max tot, then min flat
    }
    #pragma unroll
    for (int s = 1; s < 64; s <<= 1) {
      unsigned long long o = __shfl_xor(best, s, 64);
      if (o > best) best = o;
    }
    if (lane == 0) s_part[wid] = best;
    __syncthreads();
    if (tid == 0) {
      unsigned long long b = s_part[0];
      for (int i = 1; i < 16; ++i) if (s_part[i] > b) b = s_part[i];
      float tot = __uint_as_float((unsigned)(b >> 25));
      if (b != 0 && tot > 0.f) {
        int flat = (int)(0x1FFFFFFull - (b & 0x1FFFFFFull));
        int c = flat / NPIX, p = flat % NPIX;
        winners_out[round * 3 + 0] = (float)c;
        winners_out[round * 3 + 1] = (float)(p / 126);
        winners_out[round * 3 + 2] = (float)(p % 126);
        s_fr[c] = 1;
        s_sel = p;
      } else {
        winners_out[round * 3 + 0] = -1.f;
        winners_out[round * 3 + 1] = -1.f;
        winners_out[round * 3 + 2] = -1.f;
        s_sel = -1;
      }
    }
    __syncthreads();
    int sel = s_sel;
    if (sel >= 0) {
      int rw = sel / 126, cw = sel % 126;
      for (int p = tid; p < NPIX; p += 1024) {
        int row = p / 126, col = p % 126;
        if (row >= rw - 1 && row <= rw + 1 && col >= cw - 1 && col <= cw + 1)
          s_rem[p] = 1;
      }
    }
    __syncthreads();
  }
}

// ---------------- launch ----------------
extern "C" void kernel_launch(void* const* d_in, const int* in_sizes, int n_in,
                              void* d_out, int out_size, void* d_ws, size_t ws_size,
                              hipStream_t stream) {
  const int*   inp = (const int*)d_in[0];
  const float* w1  = (const float*)d_in[2];
  const float* w2  = (const float*)d_in[3];

  float* out = (float*)d_out;
  float* spk_out = out;                       // [15,250,126,126]
  float* pot_out = out + SPK_ELEMS;           // [15,250,126,126]
  float* win_out = out + 2 * SPK_ELEMS;       // [8,3]

  float* ws = (float*)d_ws;
  float* spk_in   = ws;                               // 7,372,800
  float* meta_val = ws + 7372800;                     //   238,140 (reused as pvbuf)
  int*   meta_f   = (int*)ws + 7610940;               //   238,140
  int*   winfeat  = (int*)ws + 7849080;               //    15,876
  float* cand_val = ws + 7864956;                     //    15,876
  int*   cand_n   = (int*)ws + 7880832;               //    15,876
  float* Sthr     = ws + 7896708;                     //       256
  float* consts   = ws + 7896964;                     //         4
  float* wT       = ws + 7896968;                     //    69,120 -> ends 7,966,088
  unsigned char* allones = (unsigned char*)(ws + 7966088);        // 238,140 B
  unsigned long long* bitm = (unsigned long long*)(ws + 8025624); // 115,200 ull (16B-aligned)

  hipMemsetAsync(spk_in, 0, 7372800 * sizeof(float), stream);     // pad ring
  hipMemsetAsync(bitm, 0, 115200 * sizeof(unsigned long long), stream); // pad rows 0/127
  hipMemsetAsync(out, 0, 2 * SPK_ELEMS * sizeof(float), stream);  // scatter-fill

  consts_k<<<271, 256, 0, stream>>>(w2, wT, Sthr, consts);
  {
    dim3 g(126, 6, 15);
    conv1_v4b<<<g, 128, 0, stream>>>(inp, w1, spk_in, bitm);
  }
  {
    dim3 g(126, 15);
    classify2<<<g, 128, 0, stream>>>(bitm, consts, meta_val, meta_f, allones);
  }
  dense_meta<<<1024, 256, 0, stream>>>(spk_in, wT, allones, meta_val, meta_f);
  inhibit2<<<(NPIX + 255) / 256, 256, 0, stream>>>(meta_val, meta_f, winfeat);
  winner_pv<<<(NTP + 255) / 256, 256, 0, stream>>>(
      winfeat, allones, Sthr, spk_in, w2, spk_out, pot_out, meta_val /*pvbuf*/);
  cand_k<<<(NPIX + 255) / 256, 256, 0, stream>>>(winfeat, meta_val, cand_val, cand_n);
  kwin_select2<<<1, 1024, 0, stream>>>(cand_val, cand_n, winfeat, win_out);
}

// Round 11
// 767.784 us; speedup vs baseline: 3.3925x; 1.0362x over previous
//
#include <hip/hip_runtime.h>
#include <limits.h>

#define T_STEPS 15
#define CIN     6
#define HIN     252
#define C1      30
#define SH      128
#define SW      128
#define C2      250
#define NPIX    15876          // 126*126
#define NTP     (T_STEPS*NPIX) // 238140
#define THR1    15.0f
#define THR2    10.0f
#define KWTA    8
#define SPK_ELEMS  59535000L   // 15*250*126*126

// ========== K0: weight transpose + ordered per-feature sums + argmax consts ==========
__global__ __launch_bounds__(256) void consts_k(
    const float* __restrict__ w2, float* __restrict__ wT,
    float* __restrict__ Sthr, float* __restrict__ consts) {
  const int f = threadIdx.x;
  if (blockIdx.x < 270) {
    int k = blockIdx.x;
    wT[k * 256 + f] = (f < C2) ? w2[(long)f * 270 + k] : 0.f;
    return;
  }
  __shared__ float sS[256];
  float S = 0.f;
  if (f < C2) {
    const float* wf = w2 + (long)f * 270;
    for (int k = 0; k < 270; ++k) S = fmaf(wf[k], 1.0f, S);  // == sequential add
  }
  float st = (f < C2 && S > THR2) ? S : 0.f;
  Sthr[f] = st;
  sS[f] = (f < C2) ? st : -1.f;
  __syncthreads();
  if (f == 0) {
    float bv = -1.f; int bf = 0;
    for (int i = 0; i < C2; ++i) { if (sS[i] > bv) { bv = sS[i]; bf = i; } }
    consts[0] = bv;                // thresholded max (>=0)
    ((int*)consts)[1] = bf;        // first-max feature
  }
}

// ========== K1: conv1 + fire + pool + pad1 — 2 pooled rows/block, dbuf LDS ==========
// grid (63 row-pairs, 6 channel-groups of 5, 15 t), block 256 = 2 groups x 128 lanes.
// Per ic: 8 padded rows staged (8KB), double-buffered; group gr uses rows 2gr..2gr+5.
// Per-accumulator order: ic asc, kh asc, kw asc — bitwise = reference.
#define G1 5
__global__ __launch_bounds__(256, 4) void conv1_v5(
    const int* __restrict__ inp, const float* __restrict__ w1,
    float* __restrict__ spk_in, unsigned long long* __restrict__ bitm) {
  __shared__ float srow[2][8][256];   // [buf][rr][padded col] = 16 KB
  __shared__ unsigned long long s_bal[4][G1];
  const int bx = blockIdx.x;
  const int cg = blockIdx.y;
  const int t  = blockIdx.z;
  const int tid = threadIdx.x;
  const int gr = tid >> 7, pw = tid & 127;
  const int rowbase = 4 * bx - 2;
  const int in_col = tid - 2;
  const bool colok = (in_col >= 0) && (in_col < HIN);

  float acc[G1][4];
  #pragma unroll
  for (int cc = 0; cc < G1; ++cc) {
    acc[cc][0] = 0.f; acc[cc][1] = 0.f; acc[cc][2] = 0.f; acc[cc][3] = 0.f;
  }

  // stage ic=0 into buf 0 (thread = col, coalesced per row)
  {
    const int* base = inp + ((long)(t * CIN + 0) * HIN) * HIN;
    #pragma unroll
    for (int j = 0; j < 8; ++j) {
      int row = rowbase + j;
      float v = 0.f;
      if (row >= 0 && row < HIN && colok) v = (float)base[row * HIN + in_col];
      srow[0][j][tid] = v;
    }
  }
  __syncthreads();

  for (int ic = 0; ic < CIN; ++ic) {
    const int b = ic & 1;
    if (ic < CIN - 1) {               // overlap next-ic stage with compute
      const int* base = inp + ((long)(t * CIN + ic + 1) * HIN) * HIN;
      #pragma unroll
      for (int j = 0; j < 8; ++j) {
        int row = rowbase + j;
        float v = 0.f;
        if (row >= 0 && row < HIN && colok) v = (float)base[row * HIN + in_col];
        srow[b ^ 1][j][tid] = v;
      }
    }
    #pragma unroll
    for (int r = 0; r < 6; ++r) {     // local row within group
      float row6[6];
      #pragma unroll
      for (int j = 0; j < 6; ++j)
        row6[j] = srow[b][2 * gr + r][(2 * pw + j) & 255];  // lanes pw>=126 discarded
      #pragma unroll
      for (int cc = 0; cc < G1; ++cc) {
        const int c = cg * G1 + cc;
        const float* wp = w1 + ((c * CIN) + ic) * 25;       // wave-uniform -> s_load
        if (r < 5) {                  // kh = r for output row 2ph
          #pragma unroll
          for (int kw = 0; kw < 5; ++kw) {
            float wv = wp[r * 5 + kw];
            acc[cc][0] = fmaf(wv, row6[kw],     acc[cc][0]);
            acc[cc][1] = fmaf(wv, row6[kw + 1], acc[cc][1]);
          }
        }
        if (r >= 1) {                 // kh = r-1 for output row 2ph+1
          #pragma unroll
          for (int kw = 0; kw < 5; ++kw) {
            float wv = wp[(r - 1) * 5 + kw];
            acc[cc][2] = fmaf(wv, row6[kw],     acc[cc][2]);
            acc[cc][3] = fmaf(wv, row6[kw + 1], acc[cc][3]);
          }
        }
      }
    }
    __syncthreads();                  // buf[b^1] staged; buf[b] free for overwrite
  }

  const int ph = 2 * bx + gr;         // 0..125
  unsigned fbits = 0;
  #pragma unroll
  for (int cc = 0; cc < G1; ++cc) {
    bool fired = (pw < 126) && (acc[cc][0] > THR1 || acc[cc][1] > THR1 ||
                                acc[cc][2] > THR1 || acc[cc][3] > THR1);
    if (fired) fbits |= 1u << cc;
    if (pw < 126) {
      int c = cg * G1 + cc;
      spk_in[((long)(t * C1 + c) * SH + (ph + 1)) * SW + (pw + 1)] = fired ? 1.f : 0.f;
    }
  }
  #pragma unroll
  for (int cc = 0; cc < G1; ++cc) {
    unsigned long long bl = __ballot((fbits >> cc) & 1);
    if ((tid & 63) == 0) s_bal[tid >> 6][cc] = bl;
  }
  __syncthreads();
  if (tid < 2 * G1) {
    int gr2 = tid / G1, cc = tid % G1;
    unsigned long long b0 = s_bal[2 * gr2 + 0][cc], b1 = s_bal[2 * gr2 + 1][cc];
    unsigned long long w0 = b0 << 1;
    unsigned long long w1 = (b1 << 1) | (b0 >> 63);
    int c = cg * G1 + cc;
    unsigned long long* bp = bitm + 2 * (((long)(t * C1 + c)) * SH + (2 * bx + gr2 + 1));
    bp[0] = w0; bp[1] = w1;
  }
}

// ========== K2: classify via bitmasks (all-ones window?) + constant meta ==========
__global__ __launch_bounds__(128) void classify2(
    const unsigned long long* __restrict__ bitm, const float* __restrict__ consts,
    float* __restrict__ meta_val, int* __restrict__ meta_f,
    unsigned char* __restrict__ allones) {
  const int oh = blockIdx.x, t = blockIdx.y, ow = threadIdx.x;
  unsigned long long lo = ~0ull, hi = ~0ull;
  for (int c = 0; c < C1; ++c) {
    const unsigned long long* bp = bitm + 2 * (((long)(t * C1 + c)) * SH + oh);
    lo &= bp[0] & bp[2] & bp[4];     // rows oh, oh+1, oh+2
    hi &= bp[1] & bp[3] & bp[5];
  }
  if (ow >= 126) return;
  unsigned long long x = (ow < 64)
      ? ((lo >> ow) | (ow ? (hi << (64 - ow)) : 0ull))
      : (hi >> (ow - 64));
  bool ao = (x & 7ull) == 7ull;      // cols ow, ow+1, ow+2 all ones across 30 ch
  int tp = t * NPIX + oh * 126 + ow;
  allones[tp] = ao ? 1 : 0;
  if (ao) { meta_val[tp] = consts[0]; meta_f[tp] = ((const int*)consts)[1]; }
}

// ========== K3: dense fallback for non-all-ones (t,p) — full 250-feature conv ==========
// grid MUST be 1024 blocks. Block b owns items {b + j*1024}; <=233 items/block.
__global__ __launch_bounds__(256) void dense_meta(
    const float* __restrict__ spk_in, const float* __restrict__ wT,
    const unsigned char* __restrict__ allones,
    float* __restrict__ meta_val, int* __restrict__ meta_f) {
  __shared__ int s_list[256];
  __shared__ int s_cnt;
  __shared__ float s_win[270][8];
  __shared__ unsigned long long s_part[4];
  const int tid = threadIdx.x;
  if (tid == 0) s_cnt = 0;
  __syncthreads();
  {
    int i = blockIdx.x + tid * 1024;
    if (i < NTP && !allones[i]) { int pos = atomicAdd(&s_cnt, 1); s_list[pos] = i; }
  }
  __syncthreads();
  const int cnt = s_cnt;
  for (int g = 0; g < cnt; g += 8) {
    int m = cnt - g; if (m > 8) m = 8;
    for (int j = tid; j < 270 * 8; j += 256) {
      int k = j >> 3, q = j & 7;
      float v = 0.f;
      if (q < m) {
        int tp = s_list[g + q];
        int t = tp / NPIX, p = tp % NPIX;
        int oh = p / 126, ow = p % 126;
        int c = k / 9, kh = (k % 9) / 3, kw = k % 3;
        v = spk_in[((long)(t * C1 + c) * SH + oh + kh) * SW + ow + kw];
      }
      s_win[k][q] = v;
    }
    __syncthreads();
    float acc[8];
    #pragma unroll
    for (int q = 0; q < 8; ++q) acc[q] = 0.f;
    for (int k = 0; k < 270; ++k) {          // k = (c,kh,kw) ascending = ref order
      float wv = wT[k * 256 + tid];          // coalesced
      #pragma unroll
      for (int q = 0; q < 8; ++q)
        acc[q] = fmaf(wv, s_win[k][q], acc[q]);
    }
    #pragma unroll
    for (int q = 0; q < 8; ++q) {
      unsigned long long key = 0;            // invalid lanes lose to any f<250
      if (tid < C2) {
        float v = acc[q] > THR2 ? acc[q] : 0.f;
        key = ((unsigned long long)__float_as_uint(v) << 8) | (unsigned)(255 - tid);
      }
      #pragma unroll
      for (int s = 1; s < 64; s <<= 1) {
        unsigned long long o = __shfl_xor(key, s, 64);
        if (o > key) key = o;
      }
      if ((tid & 63) == 0) s_part[tid >> 6] = key;
      __syncthreads();
      if (tid == 0 && q < m) {
        unsigned long long k0 = s_part[0];
        if (s_part[1] > k0) k0 = s_part[1];
        if (s_part[2] > k0) k0 = s_part[2];
        if (s_part[3] > k0) k0 = s_part[3];
        int tp = s_list[g + q];
        meta_val[tp] = __uint_as_float((unsigned)(k0 >> 8));
        meta_f[tp] = 255 - (int)(k0 & 255);
      }
      __syncthreads();
    }
  }
}

// ========== K4: per-pixel winner feature ==========
__global__ __launch_bounds__(256) void inhibit2(
    const float* __restrict__ meta_val, const int* __restrict__ meta_f,
    int* __restrict__ winfeat) {
  int p = blockIdx.x * 256 + threadIdx.x;
  if (p >= NPIX) return;
  int n = 0; bool last = false;
  #pragma unroll
  for (int t = 0; t < T_STEPS; ++t) {
    bool fr = meta_val[t * NPIX + p] > 0.f;
    n += fr ? 1 : 0;
    if (t == T_STEPS - 1) last = fr;
  }
  int e = T_STEPS - n;
  if (e > T_STEPS - 1) e = T_STEPS - 1;
  if (e < 0) e = 0;
  winfeat[p] = last ? meta_f[e * NPIX + p] : -1;
}

// ========== K5a: per-(t,p) winner potential + output scatter ==========
__global__ __launch_bounds__(256) void winner_pv(
    const int* __restrict__ winfeat, const unsigned char* __restrict__ allones,
    const float* __restrict__ Sthr, const float* __restrict__ spk_in,
    const float* __restrict__ w2, float* __restrict__ spk_out,
    float* __restrict__ pot_out, float* __restrict__ pvbuf) {
  int tp = blockIdx.x * 256 + threadIdx.x;
  if (tp >= NTP) return;
  int t = tp / NPIX, p = tp % NPIX;
  int w = winfeat[p];
  if (w < 0) { pvbuf[tp] = 0.f; return; }
  float pt;
  if (allones[tp]) {
    pt = Sthr[w];                            // bitwise = ordered dense sum, thresholded
  } else {
    int oh = p / 126, ow = p % 126;
    const float* wb = w2 + (long)w * 270;
    float a = 0.f;
    for (int c = 0; c < C1; ++c) {
      const float* sb = spk_in + ((long)(t * C1 + c) * SH + oh) * SW + ow;
      #pragma unroll
      for (int kh = 0; kh < 3; ++kh)
        #pragma unroll
        for (int kw = 0; kw < 3; ++kw)
          a = fmaf(wb[c * 9 + kh * 3 + kw], sb[kh * SW + kw], a);
    }
    pt = a > THR2 ? a : 0.f;
  }
  pvbuf[tp] = pt;
  long o = ((long)t * C2 + w) * NPIX + p;
  pot_out[o] = pt;
  spk_out[o] = pt > 0.f ? 1.f : 0.f;
}

// ========== K5b: per-pixel candidate (n, value at earliest) ==========
__global__ __launch_bounds__(256) void cand_k(
    const int* __restrict__ winfeat, const float* __restrict__ pvbuf,
    float* __restrict__ cand_val, int* __restrict__ cand_n) {
  int p = blockIdx.x * 256 + threadIdx.x;
  if (p >= NPIX) return;
  int w = winfeat[p];
  if (w < 0) { cand_val[p] = 0.f; cand_n[p] = 0; return; }
  float pv[T_STEPS]; int n = 0;
  #pragma unroll
  for (int t = 0; t < T_STEPS; ++t) {
    float v = pvbuf[t * NPIX + p];
    pv[t] = v;
    n += v > 0.f ? 1 : 0;
  }
  int e = T_STEPS - n; if (e > 14) e = 14; if (e < 0) e = 0;
  float cv = 0.f;
  #pragma unroll
  for (int t = 0; t < T_STEPS; ++t) if (t == e) cv = pv[t];   // static indexing
  cand_val[p] = cv;
  cand_n[p] = n;
}

// ========== K6: LDS-resident 8-round argmax + NMS (single block) ==========
__global__ __launch_bounds__(1024) void kwin_select2(
    const float* __restrict__ cand_val, const int* __restrict__ cand_n,
    const int* __restrict__ winfeat, float* __restrict__ winners_out) {
  __shared__ float s_tot[NPIX];              // 63.5 KB
  __shared__ unsigned char s_w[NPIX];        // 15.9 KB (255 = none)
  __shared__ unsigned char s_rem[NPIX];      // 15.9 KB
  __shared__ unsigned char s_fr[256];
  __shared__ unsigned long long s_part[16];
  __shared__ float s_max[16];
  __shared__ int s_sel;
  const int tid = threadIdx.x;
  const int wid = tid >> 6, lane = tid & 63;

  if (tid < 256) s_fr[tid] = 0;

  float m = 0.f;
  for (int p = tid; p < NPIX; p += 1024) {
    int w = winfeat[p];
    s_w[p] = (w < 0) ? 255 : (unsigned char)w;
    s_rem[p] = 0;
    float cv = cand_val[p];
    s_tot[p] = cv;                           // temp: cv
    m = fmaxf(m, cv);
  }
  #pragma unroll
  for (int s = 1; s < 64; s <<= 1) m = fmaxf(m, __shfl_xor(m, s, 64));
  if (lane == 0) s_max[wid] = m;
  __syncthreads();
  if (tid == 0) {
    float mm = s_max[0];
    for (int i = 1; i < 16; ++i) mm = fmaxf(mm, s_max[i]);
    s_max[0] = mm * (float)T_STEPS;          // v = T * max(trunc)
  }
  __syncthreads();
  const float v = s_max[0];
  for (int p = tid; p < NPIX; p += 1024) {
    float x = s_tot[p] + v;
    int n = cand_n[p];
    float tot = 0.f;
    for (int q = 0; q < n; ++q) tot += x;    // sequential n-term sum = ref bitwise
    s_tot[p] = tot;
  }
  __syncthreads();

  for (int round = 0; round < KWTA; ++round) {
    unsigned long long best = 0;
    for (int p = tid; p < NPIX; p += 1024) {
      unsigned char w = s_w[p];
      if (w == 255 || s_rem[p] || s_fr[w]) continue;
      unsigned long long flat = (unsigned long long)w * NPIX + (unsigned)p; // <2^22
      unsigned long long key =
          ((unsigned long long)__float_as_uint(s_tot[p]) << 25) | (0x1FFFFFFull - flat);
      if (key > best) best = key;            // max tot, then min flat
    }
    #pragma unroll
    for (int s = 1; s < 64; s <<= 1) {
      unsigned long long o = __shfl_xor(best, s, 64);
      if (o > best) best = o;
    }
    if (lane == 0) s_part[wid] = best;
    __syncthreads();
    if (tid == 0) {
      unsigned long long b = s_part[0];
      for (int i = 1; i < 16; ++i) if (s_part[i] > b) b = s_part[i];
      float tot = __uint_as_float((unsigned)(b >> 25));
      if (b != 0 && tot > 0.f) {
        int flat = (int)(0x1FFFFFFull - (b & 0x1FFFFFFull));
        int c = flat / NPIX, p = flat % NPIX;
        winners_out[round * 3 + 0] = (float)c;
        winners_out[round * 3 + 1] = (float)(p / 126);
        winners_out[round * 3 + 2] = (float)(p % 126);
        s_fr[c] = 1;
        s_sel = p;
      } else {
        winners_out[round * 3 + 0] = -1.f;
        winners_out[round * 3 + 1] = -1.f;
        winners_out[round * 3 + 2] = -1.f;
        s_sel = -1;
      }
    }
    __syncthreads();
    int sel = s_sel;
    if (sel >= 0) {
      int rw = sel / 126, cw = sel % 126;
      for (int p = tid; p < NPIX; p += 1024) {
        int row = p / 126, col = p % 126;
        if (row >= rw - 1 && row <= rw + 1 && col >= cw - 1 && col <= cw + 1)
          s_rem[p] = 1;
      }
    }
    __syncthreads();
  }
}

// ---------------- launch ----------------
extern "C" void kernel_launch(void* const* d_in, const int* in_sizes, int n_in,
                              void* d_out, int out_size, void* d_ws, size_t ws_size,
                              hipStream_t stream) {
  const int*   inp = (const int*)d_in[0];
  const float* w1  = (const float*)d_in[2];
  const float* w2  = (const float*)d_in[3];

  float* out = (float*)d_out;
  float* spk_out = out;                       // [15,250,126,126]
  float* pot_out = out + SPK_ELEMS;           // [15,250,126,126]
  float* win_out = out + 2 * SPK_ELEMS;       // [8,3]

  float* ws = (float*)d_ws;
  float* spk_in   = ws;                               // 7,372,800
  float* meta_val = ws + 7372800;                     //   238,140 (reused as pvbuf)
  int*   meta_f   = (int*)ws + 7610940;               //   238,140
  int*   winfeat  = (int*)ws + 7849080;               //    15,876
  float* cand_val = ws + 7864956;                     //    15,876
  int*   cand_n   = (int*)ws + 7880832;               //    15,876
  float* Sthr     = ws + 7896708;                     //       256
  float* consts   = ws + 7896964;                     //         4
  float* wT       = ws + 7896968;                     //    69,120 -> ends 7,966,088
  unsigned char* allones = (unsigned char*)(ws + 7966088);        // 238,140 B
  unsigned long long* bitm = (unsigned long long*)(ws + 8025624); // 115,200 ull (16B-aligned)

  hipMemsetAsync(spk_in, 0, 7372800 * sizeof(float), stream);     // pad ring
  hipMemsetAsync(bitm, 0, 115200 * sizeof(unsigned long long), stream); // pad rows 0/127
  hipMemsetAsync(out, 0, 2 * SPK_ELEMS * sizeof(float), stream);  // scatter-fill

  consts_k<<<271, 256, 0, stream>>>(w2, wT, Sthr, consts);
  {
    dim3 g(63, 6, 15);
    conv1_v5<<<g, 256, 0, stream>>>(inp, w1, spk_in, bitm);
  }
  {
    dim3 g(126, 15);
    classify2<<<g, 128, 0, stream>>>(bitm, consts, meta_val, meta_f, allones);
  }
  dense_meta<<<1024, 256, 0, stream>>>(spk_in, wT, allones, meta_val, meta_f);
  inhibit2<<<(NPIX + 255) / 256, 256, 0, stream>>>(meta_val, meta_f, winfeat);
  winner_pv<<<(NTP + 255) / 256, 256, 0, stream>>>(
      winfeat, allones, Sthr, spk_in, w2, spk_out, pot_out, meta_val /*pvbuf*/);
  cand_k<<<(NPIX + 255) / 256, 256, 0, stream>>>(winfeat, meta_val, cand_val, cand_n);
  kwin_select2<<<1, 1024, 0, stream>>>(cand_val, cand_n, winfeat, win_out);
}

// Round 13
// 767.176 us; speedup vs baseline: 3.3952x; 1.0008x over previous
//
#include <hip/hip_runtime.h>
#include <limits.h>

#define T_STEPS 15
#define CIN     6
#define HIN     252
#define C1      30
#define SH      128
#define SW      128
#define C2      250
#define NPIX    15876          // 126*126
#define NTP     (T_STEPS*NPIX) // 238140
#define THR1    15.0f
#define THR2    10.0f
#define KWTA    8
#define SPK_ELEMS  59535000L   // 15*250*126*126

// ========== K0: weight transpose + ordered per-feature sums + argmax consts ==========
__global__ __launch_bounds__(256) void consts_k(
    const float* __restrict__ w2, float* __restrict__ wT,
    float* __restrict__ Sthr, float* __restrict__ consts) {
  const int f = threadIdx.x;
  if (blockIdx.x < 270) {
    int k = blockIdx.x;
    wT[k * 256 + f] = (f < C2) ? w2[(long)f * 270 + k] : 0.f;
    return;
  }
  __shared__ float sS[256];
  float S = 0.f;
  if (f < C2) {
    const float* wf = w2 + (long)f * 270;
    for (int k = 0; k < 270; ++k) S = fmaf(wf[k], 1.0f, S);  // == sequential add
  }
  float st = (f < C2 && S > THR2) ? S : 0.f;
  Sthr[f] = st;
  sS[f] = (f < C2) ? st : -1.f;
  __syncthreads();
  if (f == 0) {
    float bv = -1.f; int bf = 0;
    for (int i = 0; i < C2; ++i) { if (sS[i] > bv) { bv = sS[i]; bf = i; } }
    consts[0] = bv;                // thresholded max (>=0)
    ((int*)consts)[1] = bf;        // first-max feature
  }
}

// ========== K1: conv1 + fire + pool + pad1 — 2 pooled rows/block, dbuf LDS, G1=10 ==========
// grid (63 row-pairs, 3 channel-groups of 10, 15 t), block 256 = 2 groups x 128 lanes.
// Per-accumulator order: ic asc, kh asc, kw asc — bitwise = reference.
#define G1 10
__global__ __launch_bounds__(256, 4) void conv1_v6(
    const int* __restrict__ inp, const float* __restrict__ w1,
    float* __restrict__ spk_in, unsigned long long* __restrict__ bitm) {
  __shared__ float srow[2][8][256];   // [buf][rr][padded col] = 16 KB
  __shared__ unsigned long long s_bal[4][G1];
  const int bx = blockIdx.x;
  const int cg = blockIdx.y;
  const int t  = blockIdx.z;
  const int tid = threadIdx.x;
  const int gr = tid >> 7, pw = tid & 127;
  const int rowbase = 4 * bx - 2;
  const int in_col = tid - 2;
  const bool colok = (in_col >= 0) && (in_col < HIN);

  float acc[G1][4];
  #pragma unroll
  for (int cc = 0; cc < G1; ++cc) {
    acc[cc][0] = 0.f; acc[cc][1] = 0.f; acc[cc][2] = 0.f; acc[cc][3] = 0.f;
  }

  // stage ic=0 into buf 0 (thread = col, coalesced per row)
  {
    const int* base = inp + ((long)(t * CIN + 0) * HIN) * HIN;
    #pragma unroll
    for (int j = 0; j < 8; ++j) {
      int row = rowbase + j;
      float v = 0.f;
      if (row >= 0 && row < HIN && colok) v = (float)base[row * HIN + in_col];
      srow[0][j][tid] = v;
    }
  }
  __syncthreads();

  for (int ic = 0; ic < CIN; ++ic) {
    const int b = ic & 1;
    if (ic < CIN - 1) {               // overlap next-ic stage with compute
      const int* base = inp + ((long)(t * CIN + ic + 1) * HIN) * HIN;
      #pragma unroll
      for (int j = 0; j < 8; ++j) {
        int row = rowbase + j;
        float v = 0.f;
        if (row >= 0 && row < HIN && colok) v = (float)base[row * HIN + in_col];
        srow[b ^ 1][j][tid] = v;
      }
    }
    #pragma unroll
    for (int r = 0; r < 6; ++r) {     // local row within group
      float row6[6];
      #pragma unroll
      for (int j = 0; j < 6; ++j)
        row6[j] = srow[b][2 * gr + r][(2 * pw + j) & 255];  // lanes pw>=126 discarded
      #pragma unroll
      for (int cc = 0; cc < G1; ++cc) {
        const int c = cg * G1 + cc;
        const float* wp = w1 + ((c * CIN) + ic) * 25;       // wave-uniform -> s_load
        if (r < 5) {                  // kh = r for output row 2ph
          #pragma unroll
          for (int kw = 0; kw < 5; ++kw) {
            float wv = wp[r * 5 + kw];
            acc[cc][0] = fmaf(wv, row6[kw],     acc[cc][0]);
            acc[cc][1] = fmaf(wv, row6[kw + 1], acc[cc][1]);
          }
        }
        if (r >= 1) {                 // kh = r-1 for output row 2ph+1
          #pragma unroll
          for (int kw = 0; kw < 5; ++kw) {
            float wv = wp[(r - 1) * 5 + kw];
            acc[cc][2] = fmaf(wv, row6[kw],     acc[cc][2]);
            acc[cc][3] = fmaf(wv, row6[kw + 1], acc[cc][3]);
          }
        }
      }
    }
    __syncthreads();                  // buf[b^1] staged; buf[b] free for overwrite
  }

  const int ph = 2 * bx + gr;         // 0..125
  unsigned fbits = 0;
  #pragma unroll
  for (int cc = 0; cc < G1; ++cc) {
    bool fired = (pw < 126) && (acc[cc][0] > THR1 || acc[cc][1] > THR1 ||
                                acc[cc][2] > THR1 || acc[cc][3] > THR1);
    if (fired) fbits |= 1u << cc;
    if (pw < 126) {
      int c = cg * G1 + cc;
      spk_in[((long)(t * C1 + c) * SH + (ph + 1)) * SW + (pw + 1)] = fired ? 1.f : 0.f;
    }
  }
  #pragma unroll
  for (int cc = 0; cc < G1; ++cc) {
    unsigned long long bl = __ballot((fbits >> cc) & 1);
    if ((tid & 63) == 0) s_bal[tid >> 6][cc] = bl;
  }
  __syncthreads();
  if (tid < 2 * G1) {
    int gr2 = tid / G1, cc = tid % G1;
    unsigned long long b0 = s_bal[2 * gr2 + 0][cc], b1 = s_bal[2 * gr2 + 1][cc];
    unsigned long long w0 = b0 << 1;
    unsigned long long w1 = (b1 << 1) | (b0 >> 63);
    int c = cg * G1 + cc;
    unsigned long long* bp = bitm + 2 * (((long)(t * C1 + c)) * SH + (2 * bx + gr2 + 1));
    bp[0] = w0; bp[1] = w1;
  }
}

// ========== K2: classify via bitmasks (all-ones window?) + constant meta ==========
__global__ __launch_bounds__(128) void classify2(
    const unsigned long long* __restrict__ bitm, const float* __restrict__ consts,
    float* __restrict__ meta_val, int* __restrict__ meta_f,
    unsigned char* __restrict__ allones) {
  const int oh = blockIdx.x, t = blockIdx.y, ow = threadIdx.x;
  unsigned long long lo = ~0ull, hi = ~0ull;
  for (int c = 0; c < C1; ++c) {
    const unsigned long long* bp = bitm + 2 * (((long)(t * C1 + c)) * SH + oh);
    lo &= bp[0] & bp[2] & bp[4];     // rows oh, oh+1, oh+2
    hi &= bp[1] & bp[3] & bp[5];
  }
  if (ow >= 126) return;
  unsigned long long x = (ow < 64)
      ? ((lo >> ow) | (ow ? (hi << (64 - ow)) : 0ull))
      : (hi >> (ow - 64));
  bool ao = (x & 7ull) == 7ull;      // cols ow, ow+1, ow+2 all ones across 30 ch
  int tp = t * NPIX + oh * 126 + ow;
  allones[tp] = ao ? 1 : 0;
  if (ao) { meta_val[tp] = consts[0]; meta_f[tp] = ((const int*)consts)[1]; }
}

// ========== K3: dense fallback for non-all-ones (t,p) — full 250-feature conv ==========
// grid MUST be 1024 blocks. Block b owns items {b + j*1024}; <=233 items/block.
__global__ __launch_bounds__(256) void dense_meta(
    const float* __restrict__ spk_in, const float* __restrict__ wT,
    const unsigned char* __restrict__ allones,
    float* __restrict__ meta_val, int* __restrict__ meta_f) {
  __shared__ int s_list[256];
  __shared__ int s_cnt;
  __shared__ float s_win[270][8];
  __shared__ unsigned long long s_part[4];
  const int tid = threadIdx.x;
  if (tid == 0) s_cnt = 0;
  __syncthreads();
  {
    int i = blockIdx.x + tid * 1024;
    if (i < NTP && !allones[i]) { int pos = atomicAdd(&s_cnt, 1); s_list[pos] = i; }
  }
  __syncthreads();
  const int cnt = s_cnt;
  for (int g = 0; g < cnt; g += 8) {
    int m = cnt - g; if (m > 8) m = 8;
    for (int j = tid; j < 270 * 8; j += 256) {
      int k = j >> 3, q = j & 7;
      float v = 0.f;
      if (q < m) {
        int tp = s_list[g + q];
        int t = tp / NPIX, p = tp % NPIX;
        int oh = p / 126, ow = p % 126;
        int c = k / 9, kh = (k % 9) / 3, kw = k % 3;
        v = spk_in[((long)(t * C1 + c) * SH + oh + kh) * SW + ow + kw];
      }
      s_win[k][q] = v;
    }
    __syncthreads();
    float acc[8];
    #pragma unroll
    for (int q = 0; q < 8; ++q) acc[q] = 0.f;
    for (int k = 0; k < 270; ++k) {          // k = (c,kh,kw) ascending = ref order
      float wv = wT[k * 256 + tid];          // coalesced
      #pragma unroll
      for (int q = 0; q < 8; ++q)
        acc[q] = fmaf(wv, s_win[k][q], acc[q]);
    }
    #pragma unroll
    for (int q = 0; q < 8; ++q) {
      unsigned long long key = 0;            // invalid lanes lose to any f<250
      if (tid < C2) {
        float v = acc[q] > THR2 ? acc[q] : 0.f;
        key = ((unsigned long long)__float_as_uint(v) << 8) | (unsigned)(255 - tid);
      }
      #pragma unroll
      for (int s = 1; s < 64; s <<= 1) {
        unsigned long long o = __shfl_xor(key, s, 64);
        if (o > key) key = o;
      }
      if ((tid & 63) == 0) s_part[tid >> 6] = key;
      __syncthreads();
      if (tid == 0 && q < m) {
        unsigned long long k0 = s_part[0];
        if (s_part[1] > k0) k0 = s_part[1];
        if (s_part[2] > k0) k0 = s_part[2];
        if (s_part[3] > k0) k0 = s_part[3];
        int tp = s_list[g + q];
        meta_val[tp] = __uint_as_float((unsigned)(k0 >> 8));
        meta_f[tp] = 255 - (int)(k0 & 255);
      }
      __syncthreads();
    }
  }
}

// ========== K4: per-pixel winner feature ==========
__global__ __launch_bounds__(256) void inhibit2(
    const float* __restrict__ meta_val, const int* __restrict__ meta_f,
    int* __restrict__ winfeat) {
  int p = blockIdx.x * 256 + threadIdx.x;
  if (p >= NPIX) return;
  int n = 0; bool last = false;
  #pragma unroll
  for (int t = 0; t < T_STEPS; ++t) {
    bool fr = meta_val[t * NPIX + p] > 0.f;
    n += fr ? 1 : 0;
    if (t == T_STEPS - 1) last = fr;
  }
  int e = T_STEPS - n;
  if (e > T_STEPS - 1) e = T_STEPS - 1;
  if (e < 0) e = 0;
  winfeat[p] = last ? meta_f[e * NPIX + p] : -1;
}

// ========== K5: per-(t,p) winner potential + output scatter ==========
__global__ __launch_bounds__(256) void winner_pv(
    const int* __restrict__ winfeat, const unsigned char* __restrict__ allones,
    const float* __restrict__ Sthr, const float* __restrict__ spk_in,
    const float* __restrict__ w2, float* __restrict__ spk_out,
    float* __restrict__ pot_out, float* __restrict__ pvbuf) {
  int tp = blockIdx.x * 256 + threadIdx.x;
  if (tp >= NTP) return;
  int t = tp / NPIX, p = tp % NPIX;
  int w = winfeat[p];
  if (w < 0) { pvbuf[tp] = 0.f; return; }
  float pt;
  if (allones[tp]) {
    pt = Sthr[w];                            // bitwise = ordered dense sum, thresholded
  } else {
    int oh = p / 126, ow = p % 126;
    const float* wb = w2 + (long)w * 270;
    float a = 0.f;
    for (int c = 0; c < C1; ++c) {
      const float* sb = spk_in + ((long)(t * C1 + c) * SH + oh) * SW + ow;
      #pragma unroll
      for (int kh = 0; kh < 3; ++kh)
        #pragma unroll
        for (int kw = 0; kw < 3; ++kw)
          a = fmaf(wb[c * 9 + kh * 3 + kw], sb[kh * SW + kw], a);
    }
    pt = a > THR2 ? a : 0.f;
  }
  pvbuf[tp] = pt;
  long o = ((long)t * C2 + w) * NPIX + p;
  pot_out[o] = pt;
  spk_out[o] = pt > 0.f ? 1.f : 0.f;
}

// ========== K6: fused candidates + 8-round argmax + NMS (single block) ==========
__global__ __launch_bounds__(1024) void kwin_select3(
    const int* __restrict__ winfeat, const float* __restrict__ pvbuf,
    float* __restrict__ winners_out) {
  __shared__ float s_tot[NPIX];              // 63.5 KB
  __shared__ unsigned char s_w[NPIX];        // 15.9 KB (255 = none)
  __shared__ unsigned char s_n[NPIX];        // 15.9 KB
  __shared__ unsigned char s_rem[NPIX];      // 15.9 KB
  __shared__ unsigned char s_fr[256];
  __shared__ unsigned long long s_part[16];
  __shared__ float s_max[16];
  __shared__ int s_sel;
  const int tid = threadIdx.x;
  const int wid = tid >> 6, lane = tid & 63;

  if (tid < 256) s_fr[tid] = 0;

  float m = 0.f;
  for (int p = tid; p < NPIX; p += 1024) {
    int w = winfeat[p];
    s_rem[p] = 0;
    float cv = 0.f; int n = 0;
    if (w >= 0) {
      float pv[T_STEPS];
      #pragma unroll
      for (int t = 0; t < T_STEPS; ++t) {
        float v = pvbuf[t * NPIX + p];
        pv[t] = v;
        n += v > 0.f ? 1 : 0;
      }
      int e = T_STEPS - n; if (e > 14) e = 14; if (e < 0) e = 0;
      #pragma unroll
      for (int t = 0; t < T_STEPS; ++t) if (t == e) cv = pv[t];  // static indexing
    }
    s_w[p] = (w < 0) ? 255 : (unsigned char)w;
    s_n[p] = (unsigned char)n;
    s_tot[p] = cv;                           // temp: cv
    m = fmaxf(m, cv);
  }
  #pragma unroll
  for (int s = 1; s < 64; s <<= 1) m = fmaxf(m, __shfl_xor(m, s, 64));
  if (lane == 0) s_max[wid] = m;
  __syncthreads();
  if (tid == 0) {
    float mm = s_max[0];
    for (int i = 1; i < 16; ++i) mm = fmaxf(mm, s_max[i]);
    s_max[0] = mm * (float)T_STEPS;          // v = T * max(trunc)
  }
  __syncthreads();
  const float v = s_max[0];
  for (int p = tid; p < NPIX; p += 1024) {
    float x = s_tot[p] + v;
    int n = s_n[p];
    float tot = 0.f;
    for (int q = 0; q < n; ++q) tot += x;    // sequential n-term sum = ref bitwise
    s_tot[p] = tot;
  }
  __syncthreads();

  for (int round = 0; round < KWTA; ++round) {
    unsigned long long best = 0;
    for (int p = tid; p < NPIX; p += 1024) {
      unsigned char w = s_w[p];
      if (w == 255 || s_rem[p] || s_fr[w]) continue;
      unsigned long long flat = (unsigned long long)w * NPIX + (unsigned)p; // <2^22
      unsigned long long key =
          ((unsigned long long)__float_as_uint(s_tot[p]) << 25) | (0x1FFFFFFull - flat);
      if (key > best) best = key;            // max tot, then min flat
    }
    #pragma unroll
    for (int s = 1; s < 64; s <<= 1) {
      unsigned long long o = __shfl_xor(best, s, 64);
      if (o > best) best = o;
    }
    if (lane == 0) s_part[wid] = best;
    __syncthreads();
    if (tid == 0) {
      unsigned long long b = s_part[0];
      for (int i = 1; i < 16; ++i) if (s_part[i] > b) b = s_part[i];
      float tot = __uint_as_float((unsigned)(b >> 25));
      if (b != 0 && tot > 0.f) {
        int flat = (int)(0x1FFFFFFull - (b & 0x1FFFFFFull));
        int c = flat / NPIX, p = flat % NPIX;
        winners_out[round * 3 + 0] = (float)c;
        winners_out[round * 3 + 1] = (float)(p / 126);
        winners_out[round * 3 + 2] = (float)(p % 126);
        s_fr[c] = 1;
        s_sel = p;
      } else {
        winners_out[round * 3 + 0] = -1.f;
        winners_out[round * 3 + 1] = -1.f;
        winners_out[round * 3 + 2] = -1.f;
        s_sel = -1;
      }
    }
    __syncthreads();
    int sel = s_sel;
    if (sel >= 0) {
      int rw = sel / 126, cw = sel % 126;
      for (int p = tid; p < NPIX; p += 1024) {
        int row = p / 126, col = p % 126;
        if (row >= rw - 1 && row <= rw + 1 && col >= cw - 1 && col <= cw + 1)
          s_rem[p] = 1;
      }
    }
    __syncthreads();
  }
}

// ---------------- launch ----------------
extern "C" void kernel_launch(void* const* d_in, const int* in_sizes, int n_in,
                              void* d_out, int out_size, void* d_ws, size_t ws_size,
                              hipStream_t stream) {
  const int*   inp = (const int*)d_in[0];
  const float* w1  = (const float*)d_in[2];
  const float* w2  = (const float*)d_in[3];

  float* out = (float*)d_out;
  float* spk_out = out;                       // [15,250,126,126]
  float* pot_out = out + SPK_ELEMS;           // [15,250,126,126]
  float* win_out = out + 2 * SPK_ELEMS;       // [8,3]

  float* ws = (float*)d_ws;
  float* spk_in   = ws;                               // 7,372,800
  float* meta_val = ws + 7372800;                     //   238,140 (reused as pvbuf)
  int*   meta_f   = (int*)ws + 7610940;               //   238,140
  int*   winfeat  = (int*)ws + 7849080;               //    15,876
  float* Sthr     = ws + 7896708;                     //       256
  float* consts   = ws + 7896964;                     //         4
  float* wT       = ws + 7896968;                     //    69,120 -> ends 7,966,088
  unsigned char* allones = (unsigned char*)(ws + 7966088);        // 238,140 B
  unsigned long long* bitm = (unsigned long long*)(ws + 8025624); // 115,200 ull (16B-aligned)

  hipMemsetAsync(spk_in, 0, 7372800 * sizeof(float), stream);     // pad ring
  hipMemsetAsync(bitm, 0, 115200 * sizeof(unsigned long long), stream); // pad rows 0/127
  hipMemsetAsync(out, 0, 2 * SPK_ELEMS * sizeof(float), stream);  // scatter-fill

  consts_k<<<271, 256, 0, stream>>>(w2, wT, Sthr, consts);
  {
    dim3 g(63, 3, 15);
    conv1_v6<<<g, 256, 0, stream>>>(inp, w1, spk_in, bitm);
  }
  {
    dim3 g(126, 15);
    classify2<<<g, 128, 0, stream>>>(bitm, consts, meta_val, meta_f, allones);
  }
  dense_meta<<<1024, 256, 0, stream>>>(spk_in, wT, allones, meta_val, meta_f);
  inhibit2<<<(NPIX + 255) / 256, 256, 0, stream>>>(meta_val, meta_f, winfeat);
  winner_pv<<<(NTP + 255) / 256, 256, 0, stream>>>(
      winfeat, allones, Sthr, spk_in, w2, spk_out, pot_out, meta_val /*pvbuf*/);
  kwin_select3<<<1, 1024, 0, stream>>>(winfeat, meta_val, win_out);
}